// Round 14
// baseline (95.692 us; speedup 1.0000x reference)
//
#include <hip/hip_runtime.h>
#include <hip/hip_bf16.h>

typedef __bf16 bf16;
typedef __bf16 bf16x2 __attribute__((ext_vector_type(2)));
typedef __bf16 bf16x4 __attribute__((ext_vector_type(4)));
typedef __bf16 bf16x8 __attribute__((ext_vector_type(8)));
typedef float  f32x4  __attribute__((ext_vector_type(4)));
typedef float  f32x16 __attribute__((ext_vector_type(16)));

static __device__ __forceinline__ f32x4 mfma16(bf16x8 a, bf16x8 b, f32x4 c) {
  return __builtin_amdgcn_mfma_f32_16x16x32_bf16(a, b, c, 0, 0, 0);
}
static __device__ __forceinline__ f32x16 mfma32(bf16x8 a, bf16x8 b, f32x16 c) {
  return __builtin_amdgcn_mfma_f32_32x32x16_bf16(a, b, c, 0, 0, 0);
}

static __device__ __forceinline__ void gload_lds16(const bf16* g, bf16* l) {
  __builtin_amdgcn_global_load_lds(
      (const __attribute__((address_space(1))) void*)g,
      (__attribute__((address_space(3))) void*)l, 16, 0, 0);
}

static __device__ __forceinline__ int cvtpk(float lo, float hi) {
  int w;
  asm("v_cvt_pk_bf16_f32 %0, %1, %2" : "=v"(w) : "v"(lo), "v"(hi));
  return w;
}
// v_permlane32_swap_b32: x <- {x_lo, y_lo}, y <- {x_hi, y_hi}
static __device__ __forceinline__ void plswap(int& x, int& y) {
  asm("v_permlane32_swap_b32 %0, %1" : "+v"(x), "+v"(y));
}

#define VMCNT0() asm volatile("s_waitcnt vmcnt(0)" ::: "memory")
#define VMCNT2() asm volatile("s_waitcnt vmcnt(2)" ::: "memory")
#define BARRIER()                                        \
  do {                                                   \
    asm volatile("" ::: "memory");                       \
    __builtin_amdgcn_s_barrier();                        \
    asm volatile("" ::: "memory");                       \
  } while (0)

// ---------------- fused: GroupNorm (blocks 0..511) + weight cast (512..2559) ----------------
__global__ __launch_bounds__(512) void pre_kernel(const float* __restrict__ x,
                                                  const float* __restrict__ gw,
                                                  const float* __restrict__ gb,
                                                  bf16* __restrict__ xnT,
                                                  const float* __restrict__ qkv_w,
                                                  bf16* __restrict__ wq,
                                                  const float* __restrict__ proj_w,
                                                  bf16* __restrict__ wp) {
  int blk = blockIdx.x;
  int tid = threadIdx.x;
  if (blk >= 512) {
    int i = (blk - 512) * 512 + tid;
    const int na4 = 3072 * 1024 / 4;
    const float* src; bf16* dst;
    if (i < na4) { src = qkv_w; dst = wq; }
    else         { src = proj_w; dst = wp; i -= na4; }
    float4 v = ((const float4*)src)[i];
    bf16x4 o = { (bf16)v.x, (bf16)v.y, (bf16)v.z, (bf16)v.w };
    *(bf16x4*)(dst + 4ll * i) = o;
    return;
  }
  int id = blk;
  int b = id >> 7, g = (id >> 2) & 31, qtr = id & 3;
  const float* xb = x + ((size_t)b * 1024 + g * 32) * 1024;   // 32 ch x 1024 t
  float s = 0.f, sq = 0.f;
  const float4* x4 = (const float4*)xb;
  for (int i = tid; i < 8192; i += 512) {
    float4 v = x4[i];
    s  += v.x + v.y + v.z + v.w;
    sq += v.x * v.x + v.y * v.y + v.z * v.z + v.w * v.w;
  }
#pragma unroll
  for (int off = 32; off; off >>= 1) { s += __shfl_down(s, off); sq += __shfl_down(sq, off); }
  __shared__ float red[16];
  int wv = tid >> 6;
  if ((tid & 63) == 0) { red[wv] = s; red[8 + wv] = sq; }
  __syncthreads();
  s = 0.f; sq = 0.f;
#pragma unroll
  for (int i = 0; i < 8; ++i) { s += red[i]; sq += red[8 + i]; }
  float mean = s * (1.f / 32768.f);
  float var  = sq * (1.f / 32768.f) - mean * mean;
  float rstd = rsqrtf(var + 1e-5f);

  __shared__ bf16 tile[64][36];
  int c = tid >> 4, q = tid & 15;              // load role: ch c, t-quad q
  int r = tid >> 3, q2 = tid & 7;              // store role: row r, ch-quad q2
  float wc = gw[g * 32 + c] * rstd;
  float fb = gb[g * 32 + c] - mean * wc;
  for (int t0 = qtr * 256; t0 < qtr * 256 + 256; t0 += 64) {
    float4 v = *(const float4*)(xb + (size_t)c * 1024 + t0 + q * 4);
    tile[q * 4 + 0][c] = (bf16)(v.x * wc + fb);
    tile[q * 4 + 1][c] = (bf16)(v.y * wc + fb);
    tile[q * 4 + 2][c] = (bf16)(v.z * wc + fb);
    tile[q * 4 + 3][c] = (bf16)(v.w * wc + fb);
    __syncthreads();
    *(bf16x4*)&xnT[((size_t)b * 1024 + t0 + r) * 1024 + g * 32 + q2 * 4] =
        *(bf16x4*)&tile[r][q2 * 4];
    __syncthreads();
  }
}

// ---------------- QKV GEMM v2: 128x192x64, 2 blocks/CU, stage-early dbuf ----------------
__global__ __launch_bounds__(512, 2) void qkv_kernel(
    const bf16* __restrict__ A, const bf16* __restrict__ Bw,
    const float* __restrict__ bias,
    bf16* __restrict__ qkT, bf16* __restrict__ vC) {
  extern __shared__ __align__(16) bf16 smem[];
  // elems: A(d) @ d*8192 (128x64, d=0..1); B(d) @ 16384 + d*12288 (192x64)

  int tid = threadIdx.x, wid = tid >> 6, lane = tid & 63;
  int l15 = lane & 15, l4 = lane >> 4;
  int wr = wid >> 2, wc = wid & 3;            // wave tile: rows wr*64, cols wc*48
  int rsw = (l15 & 7) << 4;

  int sid = (blockIdx.x & 7) * 64 + (blockIdx.x >> 3);   // XCD chunk swizzle (512%8==0)
  int bx = sid & 15, by = (sid >> 4) & 7, z = sid >> 7;
  int m0 = by * 128, n0 = bx * 192;
  const bf16* Ab = A + (size_t)z * 1024 * 1024 + (size_t)m0 * 1024;
  const bf16* Bb = Bw + (size_t)n0 * 1024;

  int srow = tid >> 3;                    // 0..63
  int csw  = (tid & 7) ^ (srow & 7);      // pre-swizzled source chunk
  auto stageA = [&](int d, int kt) {      // 2 gloads/thread (128 rows)
    bf16* dst = smem + d * 8192;
    const bf16* src = Ab + kt * 64 + csw * 8;
#pragma unroll
    for (int L = 0; L < 2; ++L)
      gload_lds16(src + (size_t)(L * 64 + srow) * 1024, dst + (L * 512 + wid * 64) * 8);
  };
  auto stageB = [&](int d, int kt) {      // 3 gloads/thread (192 rows)
    bf16* dst = smem + 16384 + d * 12288;
    const bf16* src = Bb + kt * 64 + csw * 8;
#pragma unroll
    for (int L = 0; L < 3; ++L)
      gload_lds16(src + (size_t)(L * 64 + srow) * 1024, dst + (L * 512 + wid * 64) * 8);
  };

  f32x4 acc[4][3] = {};

  auto compute = [&](int d) {
    const char* Ab8 = (const char*)smem + d * 16384 + wr * 8192;
    const char* Bb8 = (const char*)smem + 32768 + d * 24576;
    bf16x8 bfr[3][2], af[4][2];
#pragma unroll
    for (int ni = 0; ni < 3; ++ni) {
      int rb = (wc * 48 + ni * 16 + l15) * 128;
#pragma unroll
      for (int kk = 0; kk < 2; ++kk)
        bfr[ni][kk] = *(const bf16x8*)(Bb8 + rb + ((kk * 64 + l4 * 16) ^ rsw));
    }
#pragma unroll
    for (int mi = 0; mi < 4; ++mi) {
      int rb = (mi * 16 + l15) * 128;
#pragma unroll
      for (int kk = 0; kk < 2; ++kk)
        af[mi][kk] = *(const bf16x8*)(Ab8 + rb + ((kk * 64 + l4 * 16) ^ rsw));
    }
#pragma unroll
    for (int mi = 0; mi < 4; ++mi)
#pragma unroll
      for (int ni = 0; ni < 3; ++ni)
#pragma unroll
        for (int kk = 0; kk < 2; ++kk)
          acc[mi][ni] = mfma16(af[mi][kk], bfr[ni][kk], acc[mi][ni]);
  };

  stageA(0, 0); stageB(0, 0);
  VMCNT0();
  BARRIER();

  for (int t = 0; t < 16; ++t) {
    int d = t & 1;
    if (t < 15) { stageB(d ^ 1, t + 1); stageA(d ^ 1, t + 1); }  // before compute
    compute(d);
    VMCNT0();
    BARRIER();
  }

  // ---- epilogue: bias, q/k scale, split write (single head h = bx) ----
  const float scale = 0.35355339059327373f;   // 64^-0.25
  int h = bx;
#pragma unroll
  for (int ni = 0; ni < 3; ++ni) {
    int oin = wc * 48 + ni * 16;              // 0..176, wave-uniform
    float bv = bias[n0 + oin + l15];
#pragma unroll
    for (int mi = 0; mi < 4; ++mi) {
      int tb = m0 + wr * 64 + mi * 16 + l4 * 4;
      f32x4 v = acc[mi][ni];
      if (oin < 128) {                        // q|k -> qkT[b][t][h*128 + oin]
#pragma unroll
        for (int i = 0; i < 4; ++i)
          qkT[((size_t)z * 1024 + tb + i) * 2048 + h * 128 + oin + l15] =
              (bf16)((v[i] + bv) * scale);
      } else {                                // v -> vC[(b*16+h)][c][t]
        bf16x4 st = { (bf16)(v[0] + bv), (bf16)(v[1] + bv),
                      (bf16)(v[2] + bv), (bf16)(v[3] + bv) };
        *(bf16x4*)&vC[(((size_t)z * 16 + h) * 64 + (oin - 128 + l15)) * 1024 + tb] = st;
      }
    }
  }
}

// ---------------- proj GEMM: 128x128x64, T4 counted-vmcnt pipeline ----------------
__global__ __launch_bounds__(512, 1) void proj_kernel(
    const bf16* __restrict__ A, const bf16* __restrict__ Bw,
    const float* __restrict__ bias,
    const float* __restrict__ xres, float* __restrict__ out) {
  extern __shared__ __align__(16) bf16 smem[];
  // elems: A(d) @ d*8192 (128x64, d=0..2); B(d) @ 24576 + d*8192 (128x64, d=0..1)

  int tid = threadIdx.x, wid = tid >> 6, lane = tid & 63;
  int l15 = lane & 15, l4 = lane >> 4;
  int wr = wid >> 2, wc = wid & 3;             // wave tile: rows wr*64, cols wc*32
  int rsw = (l15 & 7) << 4;

  int sid = (blockIdx.x & 7) * 32 + (blockIdx.x >> 3);   // XCD chunk swizzle
  int bx = sid & 7, by = (sid >> 3) & 7, z = sid >> 6;
  int m0 = by * 128, n0 = bx * 128;
  const bf16* Ab = A + (size_t)z * 1024 * 1024 + (size_t)m0 * 1024;
  const bf16* Bb = Bw + (size_t)n0 * 1024;

  int srow = tid >> 3;                    // 0..63
  int csw  = (tid & 7) ^ (srow & 7);      // pre-swizzled source chunk
  auto stageA = [&](int d, int kt) {      // 2 gloads/thread
    bf16* dst = smem + d * 8192;
    const bf16* src = Ab + kt * 64 + csw * 8;
#pragma unroll
    for (int L = 0; L < 2; ++L)
      gload_lds16(src + (size_t)(L * 64 + srow) * 1024, dst + (L * 512 + wid * 64) * 8);
  };
  auto stageB = [&](int d, int kt) {      // 2 gloads/thread
    bf16* dst = smem + 24576 + d * 8192;
    const bf16* src = Bb + kt * 64 + csw * 8;
#pragma unroll
    for (int L = 0; L < 2; ++L)
      gload_lds16(src + (size_t)(L * 64 + srow) * 1024, dst + (L * 512 + wid * 64) * 8);
  };

  f32x4 acc[4][2] = {};

  auto compute = [&](int ta, int tb) {
    const char* Ab8 = (const char*)smem + ta * 16384 + wr * 8192;
    const char* Bb8 = (const char*)smem + 49152 + tb * 16384;
    bf16x8 bfr[2][2], af[4][2];
#pragma unroll
    for (int ni = 0; ni < 2; ++ni) {
      int rb = (wc * 32 + ni * 16 + l15) * 128;
#pragma unroll
      for (int kk = 0; kk < 2; ++kk)
        bfr[ni][kk] = *(const bf16x8*)(Bb8 + rb + ((kk * 64 + l4 * 16) ^ rsw));
    }
#pragma unroll
    for (int mi = 0; mi < 4; ++mi) {
      int rb = (mi * 16 + l15) * 128;
#pragma unroll
      for (int kk = 0; kk < 2; ++kk)
        af[mi][kk] = *(const bf16x8*)(Ab8 + rb + ((kk * 64 + l4 * 16) ^ rsw));
    }
#pragma unroll
    for (int mi = 0; mi < 4; ++mi)
#pragma unroll
      for (int ni = 0; ni < 2; ++ni)
#pragma unroll
        for (int kk = 0; kk < 2; ++kk)
          acc[mi][ni] = mfma16(af[mi][kk], bfr[ni][kk], acc[mi][ni]);
  };

  stageA(0, 0); stageB(0, 0); stageA(1, 1);
  VMCNT2();
  BARRIER();

  for (int t = 0; t < 14; ++t) {
    stageB((t + 1) & 1, t + 1);
    stageA((t + 2) % 3, t + 2);
    compute(t % 3, t & 1);
    VMCNT2();
    BARRIER();
  }
  stageB(1, 15);
  compute(2, 0);
  VMCNT0();
  BARRIER();
  compute(0, 1);

  // ---- epilogue: bias + residual, transposed fp32 write ----
#pragma unroll
  for (int ni = 0; ni < 2; ++ni) {
    int o = n0 + wc * 32 + ni * 16 + l15;
    float bv = bias[o];
#pragma unroll
    for (int mi = 0; mi < 4; ++mi) {
      int tb = m0 + wr * 64 + mi * 16 + l4 * 4;
      size_t base = ((size_t)z * 1024 + o) * 1024 + tb;
      float4 xr = *(const float4*)(xres + base);
      f32x4 v = acc[mi][ni];
      float4 ov = { xr.x + v[0] + bv, xr.y + v[1] + bv,
                    xr.z + v[2] + bv, xr.w + v[3] + bv };
      *(float4*)(out + base) = ov;
    }
  }
}

// ---------------- flash attention v7: 8 waves x 32 t = 256 t-rows/block ----------------
// v6's per-wave math (32x32 MFMA + T12 in-register softmax) unchanged; each
// staged K/V tile now amortizes over 256 output rows (2x v6) -> staging
// traffic, barrier count, and K/V L2 re-reads per output all halve.
__global__ __launch_bounds__(512, 2) void attn_kernel(const bf16* __restrict__ qkT,
                                                      const bf16* __restrict__ vC,
                                                      bf16* __restrict__ aT) {
  __shared__ __align__(16) bf16 Kt[2][64 * 64];   // [buf][s][d] swizzled, 16 KB
  __shared__ __align__(16) bf16 Vt[2][64 * 64];   // [buf][c][s] swizzled, 16 KB

  int id = blockIdx.x;
  int sid = (id & 7) * 32 + (id >> 3);            // bijective XCD swizzle (256 % 8 == 0)
  int head = sid >> 2, tblk = sid & 3;
  int b = head >> 4, h = head & 15;
  int t0 = tblk * 256;
  int tid = threadIdx.x, wid = tid >> 6, lane = tid & 63;
  int l31 = lane & 31, hi = lane >> 5;
  int trow = t0 + wid * 32;                       // 32 t-rows per wave, 8 waves

  const bf16* kbase = qkT + (size_t)b * 1024 * 2048 + h * 128 + 64;
  const bf16* vbase = vC + (size_t)(b * 16 + h) * 64 * 1024;
  int rsw = (lane & 7) << 4;                      // row-XOR ((l31)&7 == lane&7)

  // Q frags: B-operand of mfma32 — col t = l31, k(d) = kb*16 + hi*8 + j
  const bf16* qrow = qkT + ((size_t)b * 1024 + trow + l31) * 2048 + h * 128;
  bf16x8 qf[4];
#pragma unroll
  for (int kb = 0; kb < 4; ++kb) qf[kb] = *(const bf16x8*)(qrow + kb * 16 + hi * 8);

  // stage: wave wid owns 8-row group wid of K and V (1 K + 1 V gload/thread)
  int rl = lane >> 3;
  int scol = (((lane & 7) * 16) ^ (rl << 4)) >> 1;
  int r8 = wid * 8 + rl;
  auto stage = [&](int buf, int st) {
    int s0 = st * 64;
    gload_lds16(kbase + (size_t)(s0 + r8) * 2048 + scol, &Kt[buf][wid * 512]);
    gload_lds16(vbase + (size_t)r8 * 1024 + s0 + scol, &Vt[buf][wid * 512]);
  };

  float m_run = -1e30f, l_run = 0.f;
  f32x16 oacc[2] = {};                            // O^T[c][t]: col t=l31, 2 c-blocks

  stage(0, 0);
  __syncthreads();

  for (int st = 0; st < 16; ++st) {
    int cur = st & 1;
    if (st < 15) stage(cur ^ 1, st + 1);

    // ---- QK^T swapped: S^T[s][t], 8 mfma32 ----
    const char* Kb = (const char*)Kt[cur];
    f32x16 sf[2] = {};
    __builtin_amdgcn_s_setprio(1);
#pragma unroll
    for (int sb = 0; sb < 2; ++sb) {
      int rowb = (sb * 32 + l31) * 128;           // A-frag row = s
#pragma unroll
      for (int kb = 0; kb < 4; ++kb) {
        bf16x8 kf = *(const bf16x8*)(Kb + rowb + ((kb * 32 + hi * 16) ^ rsw));
        sf[sb] = mfma32(kf, qf[kb], sf[sb]);
      }
    }
    __builtin_amdgcn_s_setprio(0);

    // ---- online softmax: lane owns t=l31; s = sb*32 + (r&3)+8*(r>>2)+4*hi ----
    float mb;
    {
      float m0v = fmaxf(sf[0][0], sf[0][1]);
#pragma unroll
      for (int r = 2; r < 16; ++r) m0v = fmaxf(m0v, sf[0][r]);
#pragma unroll
      for (int r = 0; r < 16; ++r) m0v = fmaxf(m0v, sf[1][r]);
      mb = m0v;
    }
    mb = fmaxf(mb, __shfl_xor(mb, 32));           // other s-half, same t
    if (!__all(mb - m_run <= 8.f)) {              // T13 defer-max
      float mn = fmaxf(m_run, mb);
      float corr = __expf(m_run - mn);
      m_run = mn;
      l_run *= corr;
#pragma unroll
      for (int cb = 0; cb < 2; ++cb)
#pragma unroll
        for (int r = 0; r < 16; ++r) oacc[cb][r] *= corr;
    }

    // ---- P = exp(S - m), packed to bf16 + permlane redistribution (T12) ----
    float sbsum = 0.f;
    bf16x8 pf[4];                                 // B-frags for 4 k-blocks of 16 s
#pragma unroll
    for (int sb = 0; sb < 2; ++sb) {
      float p[16];
#pragma unroll
      for (int r = 0; r < 16; ++r) {
        p[r] = __expf(sf[sb][r] - m_run);
        sbsum += p[r];
      }
      int w0 = cvtpk(p[0], p[1]),   w1 = cvtpk(p[2], p[3]);
      int w2 = cvtpk(p[4], p[5]),   w3 = cvtpk(p[6], p[7]);
      int w4 = cvtpk(p[8], p[9]),   w5 = cvtpk(p[10], p[11]);
      int w6 = cvtpk(p[12], p[13]), w7 = cvtpk(p[14], p[15]);
      plswap(w0, w2); plswap(w1, w3);             // ks even: s_local 0..15
      plswap(w4, w6); plswap(w5, w7);             // ks odd:  s_local 16..31
      int4 f0 = { w0, w1, w2, w3 };
      int4 f1 = { w4, w5, w6, w7 };
      pf[sb * 2 + 0] = *(bf16x8*)&f0;
      pf[sb * 2 + 1] = *(bf16x8*)&f1;
    }
    sbsum += __shfl_xor(sbsum, 32);
    l_run += sbsum;

    // ---- PV swapped: O^T += V * P, 8 mfma32 ----
    const char* Vb = (const char*)Vt[cur];
    __builtin_amdgcn_s_setprio(1);
#pragma unroll
    for (int ks = 0; ks < 4; ++ks) {
#pragma unroll
      for (int cb = 0; cb < 2; ++cb) {
        bf16x8 vf = *(const bf16x8*)(Vb + (cb * 32 + l31) * 128 + ((ks * 32 + hi * 16) ^ rsw));
        oacc[cb] = mfma32(vf, pf[ks], oacc[cb]);
      }
    }
    __builtin_amdgcn_s_setprio(0);
    __syncthreads();   // drains vmcnt(0): next tile staged & this tile's readers done
  }

  // ---- epilogue: c = cb*32 + 4*hi + 8*q + i (i = reg&3 contiguous) ----
  float rdiv = 1.f / l_run;                       // lane-local (t = l31)
  int t = trow + l31;
#pragma unroll
  for (int cb = 0; cb < 2; ++cb) {
#pragma unroll
    for (int q = 0; q < 4; ++q) {
      bf16x4 ov = { (bf16)(oacc[cb][q * 4 + 0] * rdiv), (bf16)(oacc[cb][q * 4 + 1] * rdiv),
                    (bf16)(oacc[cb][q * 4 + 2] * rdiv), (bf16)(oacc[cb][q * 4 + 3] * rdiv) };
      int c0 = h * 64 + cb * 32 + hi * 4 + q * 8;
      *(bf16x4*)&aT[((size_t)b * 1024 + t) * 1024 + c0] = ov;
    }
  }
}

extern "C" void kernel_launch(void* const* d_in, const int* in_sizes, int n_in,
                              void* d_out, int out_size, void* d_ws, size_t ws_size,
                              hipStream_t stream) {
  const float* x      = (const float*)d_in[0];
  const float* gw     = (const float*)d_in[1];
  const float* gb     = (const float*)d_in[2];
  const float* qkv_w  = (const float*)d_in[3];
  const float* qkv_b  = (const float*)d_in[4];
  const float* proj_w = (const float*)d_in[5];
  const float* proj_b = (const float*)d_in[6];
  float* out = (float*)d_out;

  char* ws = (char*)d_ws;
  bf16* wq_bf = (bf16*)(ws);                          //  6 MB: 3072x1024
  bf16* wp_bf = (bf16*)(ws + 6ll  * 1024 * 1024);     //  2 MB: 1024x1024
  bf16* xnT   = (bf16*)(ws + 8ll  * 1024 * 1024);     //  8 MB: [4][1024][1024]
  bf16* qkT   = (bf16*)(ws + 16ll * 1024 * 1024);     // 16 MB: [4][1024][2048] (q|k per head)
  bf16* vC    = (bf16*)(ws + 32ll * 1024 * 1024);     //  8 MB: [64][64][1024]
  bf16* aT    = (bf16*)(ws + 40ll * 1024 * 1024);     //  8 MB: [4][1024][1024]

  hipFuncSetAttribute(reinterpret_cast<const void*>(qkv_kernel),
                      hipFuncAttributeMaxDynamicSharedMemorySize, 81920);
  hipFuncSetAttribute(reinterpret_cast<const void*>(proj_kernel),
                      hipFuncAttributeMaxDynamicSharedMemorySize, 81920);

  pre_kernel<<<dim3(2560), dim3(512), 0, stream>>>(x, gw, gb, xnT, qkv_w, wq_bf, proj_w, wp_bf);
  qkv_kernel<<<dim3(512), dim3(512), 81920, stream>>>(xnT, wq_bf, qkv_b, qkT, vC);
  attn_kernel<<<dim3(256), dim3(512), 0, stream>>>(qkT, vC, aT);
  proj_kernel<<<dim3(256), dim3(512), 81920, stream>>>(aT, wp_bf, proj_b, x, out);
}

// Round 15
// 93.055 us; speedup vs baseline: 1.0283x; 1.0283x over previous
//
#include <hip/hip_runtime.h>
#include <hip/hip_bf16.h>

typedef __bf16 bf16;
typedef __bf16 bf16x2 __attribute__((ext_vector_type(2)));
typedef __bf16 bf16x4 __attribute__((ext_vector_type(4)));
typedef __bf16 bf16x8 __attribute__((ext_vector_type(8)));
typedef float  f32x4  __attribute__((ext_vector_type(4)));
typedef float  f32x16 __attribute__((ext_vector_type(16)));

static __device__ __forceinline__ f32x4 mfma16(bf16x8 a, bf16x8 b, f32x4 c) {
  return __builtin_amdgcn_mfma_f32_16x16x32_bf16(a, b, c, 0, 0, 0);
}
static __device__ __forceinline__ f32x16 mfma32(bf16x8 a, bf16x8 b, f32x16 c) {
  return __builtin_amdgcn_mfma_f32_32x32x16_bf16(a, b, c, 0, 0, 0);
}

static __device__ __forceinline__ void gload_lds16(const bf16* g, bf16* l) {
  __builtin_amdgcn_global_load_lds(
      (const __attribute__((address_space(1))) void*)g,
      (__attribute__((address_space(3))) void*)l, 16, 0, 0);
}

static __device__ __forceinline__ int cvtpk(float lo, float hi) {
  int w;
  asm("v_cvt_pk_bf16_f32 %0, %1, %2" : "=v"(w) : "v"(lo), "v"(hi));
  return w;
}
// v_permlane32_swap_b32: x <- {x_lo, y_lo}, y <- {x_hi, y_hi}
static __device__ __forceinline__ void plswap(int& x, int& y) {
  asm("v_permlane32_swap_b32 %0, %1" : "+v"(x), "+v"(y));
}

#define VMCNT0() asm volatile("s_waitcnt vmcnt(0)" ::: "memory")
#define BARRIER()                                        \
  do {                                                   \
    asm volatile("" ::: "memory");                       \
    __builtin_amdgcn_s_barrier();                        \
    asm volatile("" ::: "memory");                       \
  } while (0)

// ---------------- fused: GroupNorm (blocks 0..511) + weight cast (512..2559) ----------------
__global__ __launch_bounds__(512) void pre_kernel(const float* __restrict__ x,
                                                  const float* __restrict__ gw,
                                                  const float* __restrict__ gb,
                                                  bf16* __restrict__ xnT,
                                                  const float* __restrict__ qkv_w,
                                                  bf16* __restrict__ wq,
                                                  const float* __restrict__ proj_w,
                                                  bf16* __restrict__ wp) {
  int blk = blockIdx.x;
  int tid = threadIdx.x;
  if (blk >= 512) {
    int i = (blk - 512) * 512 + tid;
    const int na4 = 3072 * 1024 / 4;
    const float* src; bf16* dst;
    if (i < na4) { src = qkv_w; dst = wq; }
    else         { src = proj_w; dst = wp; i -= na4; }
    float4 v = ((const float4*)src)[i];
    bf16x4 o = { (bf16)v.x, (bf16)v.y, (bf16)v.z, (bf16)v.w };
    *(bf16x4*)(dst + 4ll * i) = o;
    return;
  }
  int id = blk;
  int b = id >> 7, g = (id >> 2) & 31, qtr = id & 3;
  const float* xb = x + ((size_t)b * 1024 + g * 32) * 1024;   // 32 ch x 1024 t
  float s = 0.f, sq = 0.f;
  const float4* x4 = (const float4*)xb;
  for (int i = tid; i < 8192; i += 512) {
    float4 v = x4[i];
    s  += v.x + v.y + v.z + v.w;
    sq += v.x * v.x + v.y * v.y + v.z * v.z + v.w * v.w;
  }
#pragma unroll
  for (int off = 32; off; off >>= 1) { s += __shfl_down(s, off); sq += __shfl_down(sq, off); }
  __shared__ float red[16];
  int wv = tid >> 6;
  if ((tid & 63) == 0) { red[wv] = s; red[8 + wv] = sq; }
  __syncthreads();
  s = 0.f; sq = 0.f;
#pragma unroll
  for (int i = 0; i < 8; ++i) { s += red[i]; sq += red[8 + i]; }
  float mean = s * (1.f / 32768.f);
  float var  = sq * (1.f / 32768.f) - mean * mean;
  float rstd = rsqrtf(var + 1e-5f);

  __shared__ bf16 tile[64][36];
  int c = tid >> 4, q = tid & 15;              // load role: ch c, t-quad q
  int r = tid >> 3, q2 = tid & 7;              // store role: row r, ch-quad q2
  float wc = gw[g * 32 + c] * rstd;
  float fb = gb[g * 32 + c] - mean * wc;
  for (int t0 = qtr * 256; t0 < qtr * 256 + 256; t0 += 64) {
    float4 v = *(const float4*)(xb + (size_t)c * 1024 + t0 + q * 4);
    tile[q * 4 + 0][c] = (bf16)(v.x * wc + fb);
    tile[q * 4 + 1][c] = (bf16)(v.y * wc + fb);
    tile[q * 4 + 2][c] = (bf16)(v.z * wc + fb);
    tile[q * 4 + 3][c] = (bf16)(v.w * wc + fb);
    __syncthreads();
    *(bf16x4*)&xnT[((size_t)b * 1024 + t0 + r) * 1024 + g * 32 + q2 * 4] =
        *(bf16x4*)&tile[r][q2 * 4];
    __syncthreads();
  }
}

// ---------------- QKV GEMM v2: 128x192x64, 2 blocks/CU, stage-early dbuf ----------------
__global__ __launch_bounds__(512, 2) void qkv_kernel(
    const bf16* __restrict__ A, const bf16* __restrict__ Bw,
    const float* __restrict__ bias,
    bf16* __restrict__ qkT, bf16* __restrict__ vC) {
  extern __shared__ __align__(16) bf16 smem[];
  // elems: A(d) @ d*8192 (128x64, d=0..1); B(d) @ 16384 + d*12288 (192x64)

  int tid = threadIdx.x, wid = tid >> 6, lane = tid & 63;
  int l15 = lane & 15, l4 = lane >> 4;
  int wr = wid >> 2, wc = wid & 3;            // wave tile: rows wr*64, cols wc*48
  int rsw = (l15 & 7) << 4;

  int sid = (blockIdx.x & 7) * 64 + (blockIdx.x >> 3);   // XCD chunk swizzle (512%8==0)
  int bx = sid & 15, by = (sid >> 4) & 7, z = sid >> 7;
  int m0 = by * 128, n0 = bx * 192;
  const bf16* Ab = A + (size_t)z * 1024 * 1024 + (size_t)m0 * 1024;
  const bf16* Bb = Bw + (size_t)n0 * 1024;

  int srow = tid >> 3;                    // 0..63
  int csw  = (tid & 7) ^ (srow & 7);      // pre-swizzled source chunk
  auto stageA = [&](int d, int kt) {      // 2 gloads/thread (128 rows)
    bf16* dst = smem + d * 8192;
    const bf16* src = Ab + kt * 64 + csw * 8;
#pragma unroll
    for (int L = 0; L < 2; ++L)
      gload_lds16(src + (size_t)(L * 64 + srow) * 1024, dst + (L * 512 + wid * 64) * 8);
  };
  auto stageB = [&](int d, int kt) {      // 3 gloads/thread (192 rows)
    bf16* dst = smem + 16384 + d * 12288;
    const bf16* src = Bb + kt * 64 + csw * 8;
#pragma unroll
    for (int L = 0; L < 3; ++L)
      gload_lds16(src + (size_t)(L * 64 + srow) * 1024, dst + (L * 512 + wid * 64) * 8);
  };

  f32x4 acc[4][3] = {};

  auto compute = [&](int d) {
    const char* Ab8 = (const char*)smem + d * 16384 + wr * 8192;
    const char* Bb8 = (const char*)smem + 32768 + d * 24576;
    bf16x8 bfr[3][2], af[4][2];
#pragma unroll
    for (int ni = 0; ni < 3; ++ni) {
      int rb = (wc * 48 + ni * 16 + l15) * 128;
#pragma unroll
      for (int kk = 0; kk < 2; ++kk)
        bfr[ni][kk] = *(const bf16x8*)(Bb8 + rb + ((kk * 64 + l4 * 16) ^ rsw));
    }
#pragma unroll
    for (int mi = 0; mi < 4; ++mi) {
      int rb = (mi * 16 + l15) * 128;
#pragma unroll
      for (int kk = 0; kk < 2; ++kk)
        af[mi][kk] = *(const bf16x8*)(Ab8 + rb + ((kk * 64 + l4 * 16) ^ rsw));
    }
#pragma unroll
    for (int mi = 0; mi < 4; ++mi)
#pragma unroll
      for (int ni = 0; ni < 3; ++ni)
#pragma unroll
        for (int kk = 0; kk < 2; ++kk)
          acc[mi][ni] = mfma16(af[mi][kk], bfr[ni][kk], acc[mi][ni]);
  };

  stageA(0, 0); stageB(0, 0);
  VMCNT0();
  BARRIER();

  for (int t = 0; t < 16; ++t) {
    int d = t & 1;
    if (t < 15) { stageB(d ^ 1, t + 1); stageA(d ^ 1, t + 1); }  // before compute
    compute(d);
    VMCNT0();
    BARRIER();
  }

  // ---- epilogue: bias, q/k scale, split write (single head h = bx) ----
  const float scale = 0.35355339059327373f;   // 64^-0.25
  int h = bx;
#pragma unroll
  for (int ni = 0; ni < 3; ++ni) {
    int oin = wc * 48 + ni * 16;              // 0..176, wave-uniform
    float bv = bias[n0 + oin + l15];
#pragma unroll
    for (int mi = 0; mi < 4; ++mi) {
      int tb = m0 + wr * 64 + mi * 16 + l4 * 4;
      f32x4 v = acc[mi][ni];
      if (oin < 128) {                        // q|k -> qkT[b][t][h*128 + oin]
#pragma unroll
        for (int i = 0; i < 4; ++i)
          qkT[((size_t)z * 1024 + tb + i) * 2048 + h * 128 + oin + l15] =
              (bf16)((v[i] + bv) * scale);
      } else {                                // v -> vC[(b*16+h)][c][t]
        bf16x4 st = { (bf16)(v[0] + bv), (bf16)(v[1] + bv),
                      (bf16)(v[2] + bv), (bf16)(v[3] + bv) };
        *(bf16x4*)&vC[(((size_t)z * 16 + h) * 64 + (oin - 128 + l15)) * 1024 + tb] = st;
      }
    }
  }
}

// ---------------- proj GEMM v2: 128x64x64, 2 blocks/CU, stage-early dbuf ----------------
// Grid = 512 = 2 blocks/CU (qkv-v2's proven mechanism: co-resident block hides
// the tile-end drain). A+B double-buffered, 48 KB LDS. Wave tile 64x16.
__global__ __launch_bounds__(512, 2) void proj_kernel(
    const bf16* __restrict__ A, const bf16* __restrict__ Bw,
    const float* __restrict__ bias,
    const float* __restrict__ xres, float* __restrict__ out) {
  extern __shared__ __align__(16) bf16 smem[];
  // elems: A(d) @ d*8192 (128x64, d=0..1); B(d) @ 16384 + d*4096 (64x64)

  int tid = threadIdx.x, wid = tid >> 6, lane = tid & 63;
  int l15 = lane & 15, l4 = lane >> 4;
  int wr = wid >> 2, wc = wid & 3;             // wave tile: rows wr*64, cols wc*16
  int rsw = (l15 & 7) << 4;

  int sid = (blockIdx.x & 7) * 64 + (blockIdx.x >> 3);   // XCD chunk swizzle (512%8==0)
  int bx = sid & 15, by = (sid >> 4) & 7, z = sid >> 7;
  int m0 = by * 128, n0 = bx * 64;
  const bf16* Ab = A + (size_t)z * 1024 * 1024 + (size_t)m0 * 1024;
  const bf16* Bb = Bw + (size_t)n0 * 1024;

  int srow = tid >> 3;                    // 0..63
  int csw  = (tid & 7) ^ (srow & 7);      // pre-swizzled source chunk
  auto stageA = [&](int d, int kt) {      // 2 gloads/thread (128 rows)
    bf16* dst = smem + d * 8192;
    const bf16* src = Ab + kt * 64 + csw * 8;
#pragma unroll
    for (int L = 0; L < 2; ++L)
      gload_lds16(src + (size_t)(L * 64 + srow) * 1024, dst + (L * 512 + wid * 64) * 8);
  };
  auto stageB = [&](int d, int kt) {      // 1 gload/thread (64 rows)
    bf16* dst = smem + 16384 + d * 4096;
    const bf16* src = Bb + kt * 64 + csw * 8;
    gload_lds16(src + (size_t)srow * 1024, dst + (wid * 64) * 8);
  };

  f32x4 acc[4] = {};

  auto compute = [&](int d) {
    const char* Ab8 = (const char*)smem + d * 16384 + wr * 8192;
    const char* Bb8 = (const char*)smem + 32768 + d * 8192;
    bf16x8 bfr[2], af[4][2];
    int rbB = (wc * 16 + l15) * 128;
#pragma unroll
    for (int kk = 0; kk < 2; ++kk)
      bfr[kk] = *(const bf16x8*)(Bb8 + rbB + ((kk * 64 + l4 * 16) ^ rsw));
#pragma unroll
    for (int mi = 0; mi < 4; ++mi) {
      int rb = (mi * 16 + l15) * 128;
#pragma unroll
      for (int kk = 0; kk < 2; ++kk)
        af[mi][kk] = *(const bf16x8*)(Ab8 + rb + ((kk * 64 + l4 * 16) ^ rsw));
    }
#pragma unroll
    for (int mi = 0; mi < 4; ++mi)
#pragma unroll
      for (int kk = 0; kk < 2; ++kk)
        acc[mi] = mfma16(af[mi][kk], bfr[kk], acc[mi]);
  };

  stageA(0, 0); stageB(0, 0);
  VMCNT0();
  BARRIER();

  for (int t = 0; t < 16; ++t) {
    int d = t & 1;
    if (t < 15) { stageB(d ^ 1, t + 1); stageA(d ^ 1, t + 1); }  // before compute
    compute(d);
    VMCNT0();
    BARRIER();
  }

  // ---- epilogue: bias + residual, transposed fp32 write ----
  int o = n0 + wc * 16 + l15;
  float bv = bias[o];
#pragma unroll
  for (int mi = 0; mi < 4; ++mi) {
    int tb = m0 + wr * 64 + mi * 16 + l4 * 4;
    size_t base = ((size_t)z * 1024 + o) * 1024 + tb;
    float4 xr = *(const float4*)(xres + base);
    f32x4 v = acc[mi];
    float4 ov = { xr.x + v[0] + bv, xr.y + v[1] + bv,
                  xr.z + v[2] + bv, xr.w + v[3] + bv };
    *(float4*)(out + base) = ov;
  }
}

// ---------------- flash attention v6: 32x32 MFMA, in-register softmax (T12) ----------------
// (round-13 best config: 4 waves x 32 t, grid 512, 2-3 blocks/CU)
__global__ __launch_bounds__(256, 3) void attn_kernel(const bf16* __restrict__ qkT,
                                                      const bf16* __restrict__ vC,
                                                      bf16* __restrict__ aT) {
  __shared__ __align__(16) bf16 Kt[2][64 * 64];   // [buf][s][d] swizzled, 16 KB
  __shared__ __align__(16) bf16 Vt[2][64 * 64];   // [buf][c][s] swizzled, 16 KB

  int id = blockIdx.x;
  int sid = (id & 7) * 64 + (id >> 3);            // bijective XCD swizzle (512 % 8 == 0)
  int head = sid >> 3, tblk = sid & 7;
  int b = head >> 4, h = head & 15;
  int t0 = tblk * 128;
  int tid = threadIdx.x, wid = tid >> 6, lane = tid & 63;
  int l31 = lane & 31, hi = lane >> 5;
  int trow = t0 + wid * 32;                       // 32 t-rows per wave

  const bf16* kbase = qkT + (size_t)b * 1024 * 2048 + h * 128 + 64;
  const bf16* vbase = vC + (size_t)(b * 16 + h) * 64 * 1024;
  int rsw = (lane & 7) << 4;                      // row-XOR ((l31)&7 == lane&7)

  // Q frags: B-operand of mfma32 — col t = l31, k(d) = kb*16 + hi*8 + j
  const bf16* qrow = qkT + ((size_t)b * 1024 + trow + l31) * 2048 + h * 128;
  bf16x8 qf[4];
#pragma unroll
  for (int kb = 0; kb < 4; ++kb) qf[kb] = *(const bf16x8*)(qrow + kb * 16 + hi * 8);

  // stage: wave wid owns 8-row groups {2*wid, 2*wid+1} of K and V
  int rl = lane >> 3;
  int scol = (((lane & 7) * 16) ^ (rl << 4)) >> 1;
  auto stage = [&](int buf, int st) {
    int s0 = st * 64;
#pragma unroll
    for (int j = 0; j < 2; ++j) {
      int g8 = wid * 2 + j;
      int r = g8 * 8 + rl;
      gload_lds16(kbase + (size_t)(s0 + r) * 2048 + scol, &Kt[buf][g8 * 512]);
      gload_lds16(vbase + (size_t)r * 1024 + s0 + scol, &Vt[buf][g8 * 512]);
    }
  };

  float m_run = -1e30f, l_run = 0.f;
  f32x16 oacc[2] = {};                            // O^T[c][t]: col t=l31, 2 c-blocks

  stage(0, 0);
  __syncthreads();

  for (int st = 0; st < 16; ++st) {
    int cur = st & 1;
    if (st < 15) stage(cur ^ 1, st + 1);

    // ---- QK^T swapped: S^T[s][t], 8 mfma32 ----
    const char* Kb = (const char*)Kt[cur];
    f32x16 sf[2] = {};
    __builtin_amdgcn_s_setprio(1);
#pragma unroll
    for (int sb = 0; sb < 2; ++sb) {
      int rowb = (sb * 32 + l31) * 128;           // A-frag row = s
#pragma unroll
      for (int kb = 0; kb < 4; ++kb) {
        bf16x8 kf = *(const bf16x8*)(Kb + rowb + ((kb * 32 + hi * 16) ^ rsw));
        sf[sb] = mfma32(kf, qf[kb], sf[sb]);
      }
    }
    __builtin_amdgcn_s_setprio(0);

    // ---- online softmax: lane owns t=l31; s = sb*32 + (r&3)+8*(r>>2)+4*hi ----
    float mb;
    {
      float m0v = fmaxf(sf[0][0], sf[0][1]);
#pragma unroll
      for (int r = 2; r < 16; ++r) m0v = fmaxf(m0v, sf[0][r]);
#pragma unroll
      for (int r = 0; r < 16; ++r) m0v = fmaxf(m0v, sf[1][r]);
      mb = m0v;
    }
    mb = fmaxf(mb, __shfl_xor(mb, 32));           // other s-half, same t
    if (!__all(mb - m_run <= 8.f)) {              // T13 defer-max
      float mn = fmaxf(m_run, mb);
      float corr = __expf(m_run - mn);
      m_run = mn;
      l_run *= corr;
#pragma unroll
      for (int cb = 0; cb < 2; ++cb)
#pragma unroll
        for (int r = 0; r < 16; ++r) oacc[cb][r] *= corr;
    }

    // ---- P = exp(S - m), packed to bf16 + permlane redistribution (T12) ----
    float sbsum = 0.f;
    bf16x8 pf[4];                                 // B-frags for 4 k-blocks of 16 s
#pragma unroll
    for (int sb = 0; sb < 2; ++sb) {
      float p[16];
#pragma unroll
      for (int r = 0; r < 16; ++r) {
        p[r] = __expf(sf[sb][r] - m_run);
        sbsum += p[r];
      }
      int w0 = cvtpk(p[0], p[1]),   w1 = cvtpk(p[2], p[3]);
      int w2 = cvtpk(p[4], p[5]),   w3 = cvtpk(p[6], p[7]);
      int w4 = cvtpk(p[8], p[9]),   w5 = cvtpk(p[10], p[11]);
      int w6 = cvtpk(p[12], p[13]), w7 = cvtpk(p[14], p[15]);
      plswap(w0, w2); plswap(w1, w3);             // ks even: s_local 0..15
      plswap(w4, w6); plswap(w5, w7);             // ks odd:  s_local 16..31
      int4 f0 = { w0, w1, w2, w3 };
      int4 f1 = { w4, w5, w6, w7 };
      pf[sb * 2 + 0] = *(bf16x8*)&f0;
      pf[sb * 2 + 1] = *(bf16x8*)&f1;
    }
    sbsum += __shfl_xor(sbsum, 32);
    l_run += sbsum;

    // ---- PV swapped: O^T += V * P, 8 mfma32 ----
    const char* Vb = (const char*)Vt[cur];
    __builtin_amdgcn_s_setprio(1);
#pragma unroll
    for (int ks = 0; ks < 4; ++ks) {
#pragma unroll
      for (int cb = 0; cb < 2; ++cb) {
        bf16x8 vf = *(const bf16x8*)(Vb + (cb * 32 + l31) * 128 + ((ks * 32 + hi * 16) ^ rsw));
        oacc[cb] = mfma32(vf, pf[ks], oacc[cb]);
      }
    }
    __builtin_amdgcn_s_setprio(0);
    __syncthreads();   // drains vmcnt(0): next tile staged & this tile's readers done
  }

  // ---- epilogue: c = cb*32 + 4*hi + 8*q + i (i = reg&3 contiguous) ----
  float rdiv = 1.f / l_run;                       // lane-local (t = l31)
  int t = trow + l31;
#pragma unroll
  for (int cb = 0; cb < 2; ++cb) {
#pragma unroll
    for (int q = 0; q < 4; ++q) {
      bf16x4 ov = { (bf16)(oacc[cb][q * 4 + 0] * rdiv), (bf16)(oacc[cb][q * 4 + 1] * rdiv),
                    (bf16)(oacc[cb][q * 4 + 2] * rdiv), (bf16)(oacc[cb][q * 4 + 3] * rdiv) };
      int c0 = h * 64 + cb * 32 + hi * 4 + q * 8;
      *(bf16x4*)&aT[((size_t)b * 1024 + t) * 1024 + c0] = ov;
    }
  }
}

extern "C" void kernel_launch(void* const* d_in, const int* in_sizes, int n_in,
                              void* d_out, int out_size, void* d_ws, size_t ws_size,
                              hipStream_t stream) {
  const float* x      = (const float*)d_in[0];
  const float* gw     = (const float*)d_in[1];
  const float* gb     = (const float*)d_in[2];
  const float* qkv_w  = (const float*)d_in[3];
  const float* qkv_b  = (const float*)d_in[4];
  const float* proj_w = (const float*)d_in[5];
  const float* proj_b = (const float*)d_in[6];
  float* out = (float*)d_out;

  char* ws = (char*)d_ws;
  bf16* wq_bf = (bf16*)(ws);                          //  6 MB: 3072x1024
  bf16* wp_bf = (bf16*)(ws + 6ll  * 1024 * 1024);     //  2 MB: 1024x1024
  bf16* xnT   = (bf16*)(ws + 8ll  * 1024 * 1024);     //  8 MB: [4][1024][1024]
  bf16* qkT   = (bf16*)(ws + 16ll * 1024 * 1024);     // 16 MB: [4][1024][2048] (q|k per head)
  bf16* vC    = (bf16*)(ws + 32ll * 1024 * 1024);     //  8 MB: [64][64][1024]
  bf16* aT    = (bf16*)(ws + 40ll * 1024 * 1024);     //  8 MB: [4][1024][1024]

  hipFuncSetAttribute(reinterpret_cast<const void*>(qkv_kernel),
                      hipFuncAttributeMaxDynamicSharedMemorySize, 81920);
  hipFuncSetAttribute(reinterpret_cast<const void*>(proj_kernel),
                      hipFuncAttributeMaxDynamicSharedMemorySize, 49152);

  pre_kernel<<<dim3(2560), dim3(512), 0, stream>>>(x, gw, gb, xnT, qkv_w, wq_bf, proj_w, wp_bf);
  qkv_kernel<<<dim3(512), dim3(512), 81920, stream>>>(xnT, wq_bf, qkv_b, qkT, vC);
  attn_kernel<<<dim3(512), dim3(256), 0, stream>>>(qkT, vC, aT);
  proj_kernel<<<dim3(512), dim3(512), 49152, stream>>>(aT, wp_bf, proj_b, x, out);
}

// Round 16
// 91.983 us; speedup vs baseline: 1.0403x; 1.0117x over previous
//
#include <hip/hip_runtime.h>
#include <hip/hip_bf16.h>

typedef __bf16 bf16;
typedef __bf16 bf16x2 __attribute__((ext_vector_type(2)));
typedef __bf16 bf16x4 __attribute__((ext_vector_type(4)));
typedef __bf16 bf16x8 __attribute__((ext_vector_type(8)));
typedef float  f32x4  __attribute__((ext_vector_type(4)));
typedef float  f32x16 __attribute__((ext_vector_type(16)));

static __device__ __forceinline__ f32x4 mfma16(bf16x8 a, bf16x8 b, f32x4 c) {
  return __builtin_amdgcn_mfma_f32_16x16x32_bf16(a, b, c, 0, 0, 0);
}
static __device__ __forceinline__ f32x16 mfma32(bf16x8 a, bf16x8 b, f32x16 c) {
  return __builtin_amdgcn_mfma_f32_32x32x16_bf16(a, b, c, 0, 0, 0);
}

static __device__ __forceinline__ void gload_lds16(const bf16* g, bf16* l) {
  __builtin_amdgcn_global_load_lds(
      (const __attribute__((address_space(1))) void*)g,
      (__attribute__((address_space(3))) void*)l, 16, 0, 0);
}

static __device__ __forceinline__ int cvtpk(float lo, float hi) {
  int w;
  asm("v_cvt_pk_bf16_f32 %0, %1, %2" : "=v"(w) : "v"(lo), "v"(hi));
  return w;
}
// v_permlane32_swap_b32: x <- {x_lo, y_lo}, y <- {x_hi, y_hi}
static __device__ __forceinline__ void plswap(int& x, int& y) {
  asm("v_permlane32_swap_b32 %0, %1" : "+v"(x), "+v"(y));
}

#define VMCNT0() asm volatile("s_waitcnt vmcnt(0)" ::: "memory")
#define BARRIER()                                        \
  do {                                                   \
    asm volatile("" ::: "memory");                       \
    __builtin_amdgcn_s_barrier();                        \
    asm volatile("" ::: "memory");                       \
  } while (0)

// ---------------- fused: GroupNorm (blocks 0..511) + weight cast (512..2559) ----------------
__global__ __launch_bounds__(512) void pre_kernel(const float* __restrict__ x,
                                                  const float* __restrict__ gw,
                                                  const float* __restrict__ gb,
                                                  bf16* __restrict__ xnT,
                                                  const float* __restrict__ qkv_w,
                                                  bf16* __restrict__ wq,
                                                  const float* __restrict__ proj_w,
                                                  bf16* __restrict__ wp) {
  int blk = blockIdx.x;
  int tid = threadIdx.x;
  if (blk >= 512) {
    int i = (blk - 512) * 512 + tid;
    const int na4 = 3072 * 1024 / 4;
    const float* src; bf16* dst;
    if (i < na4) { src = qkv_w; dst = wq; }
    else         { src = proj_w; dst = wp; i -= na4; }
    float4 v = ((const float4*)src)[i];
    bf16x4 o = { (bf16)v.x, (bf16)v.y, (bf16)v.z, (bf16)v.w };
    *(bf16x4*)(dst + 4ll * i) = o;
    return;
  }
  int id = blk;
  int b = id >> 7, g = (id >> 2) & 31, qtr = id & 3;
  const float* xb = x + ((size_t)b * 1024 + g * 32) * 1024;   // 32 ch x 1024 t
  float s = 0.f, sq = 0.f;
  const float4* x4 = (const float4*)xb;
  for (int i = tid; i < 8192; i += 512) {
    float4 v = x4[i];
    s  += v.x + v.y + v.z + v.w;
    sq += v.x * v.x + v.y * v.y + v.z * v.z + v.w * v.w;
  }
#pragma unroll
  for (int off = 32; off; off >>= 1) { s += __shfl_down(s, off); sq += __shfl_down(sq, off); }
  __shared__ float red[16];
  int wv = tid >> 6;
  if ((tid & 63) == 0) { red[wv] = s; red[8 + wv] = sq; }
  __syncthreads();
  s = 0.f; sq = 0.f;
#pragma unroll
  for (int i = 0; i < 8; ++i) { s += red[i]; sq += red[8 + i]; }
  float mean = s * (1.f / 32768.f);
  float var  = sq * (1.f / 32768.f) - mean * mean;
  float rstd = rsqrtf(var + 1e-5f);

  __shared__ bf16 tile[64][36];
  int c = tid >> 4, q = tid & 15;              // load role: ch c, t-quad q
  int r = tid >> 3, q2 = tid & 7;              // store role: row r, ch-quad q2
  float wc = gw[g * 32 + c] * rstd;
  float fb = gb[g * 32 + c] - mean * wc;
  for (int t0 = qtr * 256; t0 < qtr * 256 + 256; t0 += 64) {
    float4 v = *(const float4*)(xb + (size_t)c * 1024 + t0 + q * 4);
    tile[q * 4 + 0][c] = (bf16)(v.x * wc + fb);
    tile[q * 4 + 1][c] = (bf16)(v.y * wc + fb);
    tile[q * 4 + 2][c] = (bf16)(v.z * wc + fb);
    tile[q * 4 + 3][c] = (bf16)(v.w * wc + fb);
    __syncthreads();
    *(bf16x4*)&xnT[((size_t)b * 1024 + t0 + r) * 1024 + g * 32 + q2 * 4] =
        *(bf16x4*)&tile[r][q2 * 4];
    __syncthreads();
  }
}

// ---------------- QKV GEMM v2: 128x192x64, 2 blocks/CU, stage-early dbuf ----------------
__global__ __launch_bounds__(512, 2) void qkv_kernel(
    const bf16* __restrict__ A, const bf16* __restrict__ Bw,
    const float* __restrict__ bias,
    bf16* __restrict__ qkT, bf16* __restrict__ vC) {
  extern __shared__ __align__(16) bf16 smem[];
  // elems: A(d) @ d*8192 (128x64, d=0..1); B(d) @ 16384 + d*12288 (192x64)

  int tid = threadIdx.x, wid = tid >> 6, lane = tid & 63;
  int l15 = lane & 15, l4 = lane >> 4;
  int wr = wid >> 2, wc = wid & 3;            // wave tile: rows wr*64, cols wc*48
  int rsw = (l15 & 7) << 4;

  int sid = (blockIdx.x & 7) * 64 + (blockIdx.x >> 3);   // XCD chunk swizzle (512%8==0)
  int bx = sid & 15, by = (sid >> 4) & 7, z = sid >> 7;
  int m0 = by * 128, n0 = bx * 192;
  const bf16* Ab = A + (size_t)z * 1024 * 1024 + (size_t)m0 * 1024;
  const bf16* Bb = Bw + (size_t)n0 * 1024;

  int srow = tid >> 3;                    // 0..63
  int csw  = (tid & 7) ^ (srow & 7);      // pre-swizzled source chunk
  auto stageA = [&](int d, int kt) {      // 2 gloads/thread (128 rows)
    bf16* dst = smem + d * 8192;
    const bf16* src = Ab + kt * 64 + csw * 8;
#pragma unroll
    for (int L = 0; L < 2; ++L)
      gload_lds16(src + (size_t)(L * 64 + srow) * 1024, dst + (L * 512 + wid * 64) * 8);
  };
  auto stageB = [&](int d, int kt) {      // 3 gloads/thread (192 rows)
    bf16* dst = smem + 16384 + d * 12288;
    const bf16* src = Bb + kt * 64 + csw * 8;
#pragma unroll
    for (int L = 0; L < 3; ++L)
      gload_lds16(src + (size_t)(L * 64 + srow) * 1024, dst + (L * 512 + wid * 64) * 8);
  };

  f32x4 acc[4][3] = {};

  auto compute = [&](int d) {
    const char* Ab8 = (const char*)smem + d * 16384 + wr * 8192;
    const char* Bb8 = (const char*)smem + 32768 + d * 24576;
    bf16x8 bfr[3][2], af[4][2];
#pragma unroll
    for (int ni = 0; ni < 3; ++ni) {
      int rb = (wc * 48 + ni * 16 + l15) * 128;
#pragma unroll
      for (int kk = 0; kk < 2; ++kk)
        bfr[ni][kk] = *(const bf16x8*)(Bb8 + rb + ((kk * 64 + l4 * 16) ^ rsw));
    }
#pragma unroll
    for (int mi = 0; mi < 4; ++mi) {
      int rb = (mi * 16 + l15) * 128;
#pragma unroll
      for (int kk = 0; kk < 2; ++kk)
        af[mi][kk] = *(const bf16x8*)(Ab8 + rb + ((kk * 64 + l4 * 16) ^ rsw));
    }
#pragma unroll
    for (int mi = 0; mi < 4; ++mi)
#pragma unroll
      for (int ni = 0; ni < 3; ++ni)
#pragma unroll
        for (int kk = 0; kk < 2; ++kk)
          acc[mi][ni] = mfma16(af[mi][kk], bfr[ni][kk], acc[mi][ni]);
  };

  stageA(0, 0); stageB(0, 0);
  VMCNT0();
  BARRIER();

  for (int t = 0; t < 16; ++t) {
    int d = t & 1;
    if (t < 15) { stageB(d ^ 1, t + 1); stageA(d ^ 1, t + 1); }  // before compute
    compute(d);
    VMCNT0();
    BARRIER();
  }

  // ---- epilogue: bias, q/k scale, split write (single head h = bx) ----
  const float scale = 0.35355339059327373f;   // 64^-0.25
  int h = bx;
#pragma unroll
  for (int ni = 0; ni < 3; ++ni) {
    int oin = wc * 48 + ni * 16;              // 0..176, wave-uniform
    float bv = bias[n0 + oin + l15];
#pragma unroll
    for (int mi = 0; mi < 4; ++mi) {
      int tb = m0 + wr * 64 + mi * 16 + l4 * 4;
      f32x4 v = acc[mi][ni];
      if (oin < 128) {                        // q|k -> qkT[b][t][h*128 + oin]
#pragma unroll
        for (int i = 0; i < 4; ++i)
          qkT[((size_t)z * 1024 + tb + i) * 2048 + h * 128 + oin + l15] =
              (bf16)((v[i] + bv) * scale);
      } else {                                // v -> vC[(b*16+h)][c][t]
        bf16x4 st = { (bf16)(v[0] + bv), (bf16)(v[1] + bv),
                      (bf16)(v[2] + bv), (bf16)(v[3] + bv) };
        *(bf16x4*)&vC[(((size_t)z * 16 + h) * 64 + (oin - 128 + l15)) * 1024 + tb] = st;
      }
    }
  }
}

// ---------------- proj GEMM v2: 128x64x64, 2 blocks/CU, stage-early dbuf ----------------
__global__ __launch_bounds__(512, 2) void proj_kernel(
    const bf16* __restrict__ A, const bf16* __restrict__ Bw,
    const float* __restrict__ bias,
    const float* __restrict__ xres, float* __restrict__ out) {
  extern __shared__ __align__(16) bf16 smem[];
  // elems: A(d) @ d*8192 (128x64, d=0..1); B(d) @ 16384 + d*4096 (64x64)

  int tid = threadIdx.x, wid = tid >> 6, lane = tid & 63;
  int l15 = lane & 15, l4 = lane >> 4;
  int wr = wid >> 2, wc = wid & 3;             // wave tile: rows wr*64, cols wc*16
  int rsw = (l15 & 7) << 4;

  int sid = (blockIdx.x & 7) * 64 + (blockIdx.x >> 3);   // XCD chunk swizzle (512%8==0)
  int bx = sid & 15, by = (sid >> 4) & 7, z = sid >> 7;
  int m0 = by * 128, n0 = bx * 64;
  const bf16* Ab = A + (size_t)z * 1024 * 1024 + (size_t)m0 * 1024;
  const bf16* Bb = Bw + (size_t)n0 * 1024;

  int srow = tid >> 3;                    // 0..63
  int csw  = (tid & 7) ^ (srow & 7);      // pre-swizzled source chunk
  auto stageA = [&](int d, int kt) {      // 2 gloads/thread (128 rows)
    bf16* dst = smem + d * 8192;
    const bf16* src = Ab + kt * 64 + csw * 8;
#pragma unroll
    for (int L = 0; L < 2; ++L)
      gload_lds16(src + (size_t)(L * 64 + srow) * 1024, dst + (L * 512 + wid * 64) * 8);
  };
  auto stageB = [&](int d, int kt) {      // 1 gload/thread (64 rows)
    bf16* dst = smem + 16384 + d * 4096;
    const bf16* src = Bb + kt * 64 + csw * 8;
    gload_lds16(src + (size_t)srow * 1024, dst + (wid * 64) * 8);
  };

  f32x4 acc[4] = {};

  auto compute = [&](int d) {
    const char* Ab8 = (const char*)smem + d * 16384 + wr * 8192;
    const char* Bb8 = (const char*)smem + 32768 + d * 8192;
    bf16x8 bfr[2], af[4][2];
    int rbB = (wc * 16 + l15) * 128;
#pragma unroll
    for (int kk = 0; kk < 2; ++kk)
      bfr[kk] = *(const bf16x8*)(Bb8 + rbB + ((kk * 64 + l4 * 16) ^ rsw));
#pragma unroll
    for (int mi = 0; mi < 4; ++mi) {
      int rb = (mi * 16 + l15) * 128;
#pragma unroll
      for (int kk = 0; kk < 2; ++kk)
        af[mi][kk] = *(const bf16x8*)(Ab8 + rb + ((kk * 64 + l4 * 16) ^ rsw));
    }
#pragma unroll
    for (int mi = 0; mi < 4; ++mi)
#pragma unroll
      for (int kk = 0; kk < 2; ++kk)
        acc[mi] = mfma16(af[mi][kk], bfr[kk], acc[mi]);
  };

  stageA(0, 0); stageB(0, 0);
  VMCNT0();
  BARRIER();

  for (int t = 0; t < 16; ++t) {
    int d = t & 1;
    if (t < 15) { stageB(d ^ 1, t + 1); stageA(d ^ 1, t + 1); }  // before compute
    compute(d);
    VMCNT0();
    BARRIER();
  }

  // ---- epilogue: bias + residual, transposed fp32 write ----
  int o = n0 + wc * 16 + l15;
  float bv = bias[o];
#pragma unroll
  for (int mi = 0; mi < 4; ++mi) {
    int tb = m0 + wr * 64 + mi * 16 + l4 * 4;
    size_t base = ((size_t)z * 1024 + o) * 1024 + tb;
    float4 xr = *(const float4*)(xres + base);
    f32x4 v = acc[mi];
    float4 ov = { xr.x + v[0] + bv, xr.y + v[1] + bv,
                  xr.z + v[2] + bv, xr.w + v[3] + bv };
    *(float4*)(out + base) = ov;
  }
}

// ---------------- flash attention v8: SBLK=128 (two 64-subtiles per barrier) ----------------
// v6 math byte-identical; K/V staged as two independent 64x64 sub-tiles per
// outer tile -> barrier/drain count halves (8 outer tiles), stage->use window
// doubles. LDS 64 KB = 2 blocks/CU (occupancy unchanged vs v6).
__global__ __launch_bounds__(256, 2) void attn_kernel(const bf16* __restrict__ qkT,
                                                      const bf16* __restrict__ vC,
                                                      bf16* __restrict__ aT) {
  __shared__ __align__(16) bf16 Kt[2][2][64 * 64];   // [buf][h2][s][d] swizzled, 32 KB
  __shared__ __align__(16) bf16 Vt[2][2][64 * 64];   // [buf][h2][c][s] swizzled, 32 KB

  int id = blockIdx.x;
  int sid = (id & 7) * 64 + (id >> 3);            // bijective XCD swizzle (512 % 8 == 0)
  int head = sid >> 3, tblk = sid & 7;
  int b = head >> 4, h = head & 15;
  int t0 = tblk * 128;
  int tid = threadIdx.x, wid = tid >> 6, lane = tid & 63;
  int l31 = lane & 31, hi = lane >> 5;
  int trow = t0 + wid * 32;                       // 32 t-rows per wave

  const bf16* kbase = qkT + (size_t)b * 1024 * 2048 + h * 128 + 64;
  const bf16* vbase = vC + (size_t)(b * 16 + h) * 64 * 1024;
  int rsw = (lane & 7) << 4;                      // row-XOR ((l31)&7 == lane&7)

  // Q frags: B-operand of mfma32 — col t = l31, k(d) = kb*16 + hi*8 + j
  const bf16* qrow = qkT + ((size_t)b * 1024 + trow + l31) * 2048 + h * 128;
  bf16x8 qf[4];
#pragma unroll
  for (int kb = 0; kb < 4; ++kb) qf[kb] = *(const bf16x8*)(qrow + kb * 16 + hi * 8);

  // stage one 64x64 sub-tile (v6-proven): wave wid owns 8-row groups {2wid,2wid+1}
  int rl = lane >> 3;
  int scol = (((lane & 7) * 16) ^ (rl << 4)) >> 1;
  auto stage64 = [&](int buf, int h2, int st64) {
    int s0 = st64 * 64;
#pragma unroll
    for (int j = 0; j < 2; ++j) {
      int g8 = wid * 2 + j;
      int r = g8 * 8 + rl;
      gload_lds16(kbase + (size_t)(s0 + r) * 2048 + scol, &Kt[buf][h2][g8 * 512]);
      gload_lds16(vbase + (size_t)r * 1024 + s0 + scol, &Vt[buf][h2][g8 * 512]);
    }
  };
  auto stage = [&](int buf, int st) {             // st = outer tile (128 s)
    stage64(buf, 0, st * 2 + 0);
    stage64(buf, 1, st * 2 + 1);
  };

  float m_run = -1e30f, l_run = 0.f;
  f32x16 oacc[2] = {};                            // O^T[c][t]: col t=l31, 2 c-blocks

  stage(0, 0);
  __syncthreads();

  for (int st = 0; st < 8; ++st) {
    int cur = st & 1;
    if (st < 7) stage(cur ^ 1, st + 1);

#pragma unroll
    for (int h2 = 0; h2 < 2; ++h2) {
      // ---- QK^T swapped: S^T[s][t], 8 mfma32 ----
      const char* Kb = (const char*)Kt[cur][h2];
      f32x16 sf[2] = {};
      __builtin_amdgcn_s_setprio(1);
#pragma unroll
      for (int sb = 0; sb < 2; ++sb) {
        int rowb = (sb * 32 + l31) * 128;         // A-frag row = s
#pragma unroll
        for (int kb = 0; kb < 4; ++kb) {
          bf16x8 kf = *(const bf16x8*)(Kb + rowb + ((kb * 32 + hi * 16) ^ rsw));
          sf[sb] = mfma32(kf, qf[kb], sf[sb]);
        }
      }
      __builtin_amdgcn_s_setprio(0);

      // ---- online softmax: lane owns t=l31; s = sb*32 + (r&3)+8*(r>>2)+4*hi ----
      float mb;
      {
        float m0v = fmaxf(sf[0][0], sf[0][1]);
#pragma unroll
        for (int r = 2; r < 16; ++r) m0v = fmaxf(m0v, sf[0][r]);
#pragma unroll
        for (int r = 0; r < 16; ++r) m0v = fmaxf(m0v, sf[1][r]);
        mb = m0v;
      }
      mb = fmaxf(mb, __shfl_xor(mb, 32));         // other s-half, same t
      if (!__all(mb - m_run <= 8.f)) {            // T13 defer-max
        float mn = fmaxf(m_run, mb);
        float corr = __expf(m_run - mn);
        m_run = mn;
        l_run *= corr;
#pragma unroll
        for (int cb = 0; cb < 2; ++cb)
#pragma unroll
          for (int r = 0; r < 16; ++r) oacc[cb][r] *= corr;
      }

      // ---- P = exp(S - m), packed to bf16 + permlane redistribution (T12) ----
      float sbsum = 0.f;
      bf16x8 pf[4];                               // B-frags for 4 k-blocks of 16 s
#pragma unroll
      for (int sb = 0; sb < 2; ++sb) {
        float p[16];
#pragma unroll
        for (int r = 0; r < 16; ++r) {
          p[r] = __expf(sf[sb][r] - m_run);
          sbsum += p[r];
        }
        int w0 = cvtpk(p[0], p[1]),   w1 = cvtpk(p[2], p[3]);
        int w2 = cvtpk(p[4], p[5]),   w3 = cvtpk(p[6], p[7]);
        int w4 = cvtpk(p[8], p[9]),   w5 = cvtpk(p[10], p[11]);
        int w6 = cvtpk(p[12], p[13]), w7 = cvtpk(p[14], p[15]);
        plswap(w0, w2); plswap(w1, w3);           // ks even: s_local 0..15
        plswap(w4, w6); plswap(w5, w7);           // ks odd:  s_local 16..31
        int4 f0 = { w0, w1, w2, w3 };
        int4 f1 = { w4, w5, w6, w7 };
        pf[sb * 2 + 0] = *(bf16x8*)&f0;
        pf[sb * 2 + 1] = *(bf16x8*)&f1;
      }
      sbsum += __shfl_xor(sbsum, 32);
      l_run += sbsum;

      // ---- PV swapped: O^T += V * P, 8 mfma32 ----
      const char* Vb = (const char*)Vt[cur][h2];
      __builtin_amdgcn_s_setprio(1);
#pragma unroll
      for (int ks = 0; ks < 4; ++ks) {
#pragma unroll
        for (int cb = 0; cb < 2; ++cb) {
          bf16x8 vf = *(const bf16x8*)(Vb + (cb * 32 + l31) * 128 + ((ks * 32 + hi * 16) ^ rsw));
          oacc[cb] = mfma32(vf, pf[ks], oacc[cb]);
        }
      }
      __builtin_amdgcn_s_setprio(0);
    }
    VMCNT0();
    BARRIER();   // once per 128 s (was per 64)
  }

  // ---- epilogue: c = cb*32 + 4*hi + 8*q + i (i = reg&3 contiguous) ----
  float rdiv = 1.f / l_run;                       // lane-local (t = l31)
  int t = trow + l31;
#pragma unroll
  for (int cb = 0; cb < 2; ++cb) {
#pragma unroll
    for (int q = 0; q < 4; ++q) {
      bf16x4 ov = { (bf16)(oacc[cb][q * 4 + 0] * rdiv), (bf16)(oacc[cb][q * 4 + 1] * rdiv),
                    (bf16)(oacc[cb][q * 4 + 2] * rdiv), (bf16)(oacc[cb][q * 4 + 3] * rdiv) };
      int c0 = h * 64 + cb * 32 + hi * 4 + q * 8;
      *(bf16x4*)&aT[((size_t)b * 1024 + t) * 1024 + c0] = ov;
    }
  }
}

extern "C" void kernel_launch(void* const* d_in, const int* in_sizes, int n_in,
                              void* d_out, int out_size, void* d_ws, size_t ws_size,
                              hipStream_t stream) {
  const float* x      = (const float*)d_in[0];
  const float* gw     = (const float*)d_in[1];
  const float* gb     = (const float*)d_in[2];
  const float* qkv_w  = (const float*)d_in[3];
  const float* qkv_b  = (const float*)d_in[4];
  const float* proj_w = (const float*)d_in[5];
  const float* proj_b = (const float*)d_in[6];
  float* out = (float*)d_out;

  char* ws = (char*)d_ws;
  bf16* wq_bf = (bf16*)(ws);                          //  6 MB: 3072x1024
  bf16* wp_bf = (bf16*)(ws + 6ll  * 1024 * 1024);     //  2 MB: 1024x1024
  bf16* xnT   = (bf16*)(ws + 8ll  * 1024 * 1024);     //  8 MB: [4][1024][1024]
  bf16* qkT   = (bf16*)(ws + 16ll * 1024 * 1024);     // 16 MB: [4][1024][2048] (q|k per head)
  bf16* vC    = (bf16*)(ws + 32ll * 1024 * 1024);     //  8 MB: [64][64][1024]
  bf16* aT    = (bf16*)(ws + 40ll * 1024 * 1024);     //  8 MB: [4][1024][1024]

  hipFuncSetAttribute(reinterpret_cast<const void*>(qkv_kernel),
                      hipFuncAttributeMaxDynamicSharedMemorySize, 81920);
  hipFuncSetAttribute(reinterpret_cast<const void*>(proj_kernel),
                      hipFuncAttributeMaxDynamicSharedMemorySize, 49152);

  pre_kernel<<<dim3(2560), dim3(512), 0, stream>>>(x, gw, gb, xnT, qkv_w, wq_bf, proj_w, wp_bf);
  qkv_kernel<<<dim3(512), dim3(512), 81920, stream>>>(xnT, wq_bf, qkv_b, qkT, vC);
  attn_kernel<<<dim3(512), dim3(256), 0, stream>>>(qkT, vC, aT);
  proj_kernel<<<dim3(512), dim3(512), 49152, stream>>>(aT, wp_bf, proj_b, x, out);
}

// Round 17
// 87.547 us; speedup vs baseline: 1.0930x; 1.0507x over previous
//
#include <hip/hip_runtime.h>
#include <hip/hip_bf16.h>

typedef __bf16 bf16;
typedef __bf16 bf16x2 __attribute__((ext_vector_type(2)));
typedef __bf16 bf16x4 __attribute__((ext_vector_type(4)));
typedef __bf16 bf16x8 __attribute__((ext_vector_type(8)));
typedef float  f32x4  __attribute__((ext_vector_type(4)));
typedef float  f32x16 __attribute__((ext_vector_type(16)));

static __device__ __forceinline__ f32x4 mfma16(bf16x8 a, bf16x8 b, f32x4 c) {
  return __builtin_amdgcn_mfma_f32_16x16x32_bf16(a, b, c, 0, 0, 0);
}
static __device__ __forceinline__ f32x16 mfma32(bf16x8 a, bf16x8 b, f32x16 c) {
  return __builtin_amdgcn_mfma_f32_32x32x16_bf16(a, b, c, 0, 0, 0);
}

static __device__ __forceinline__ void gload_lds16(const bf16* g, bf16* l) {
  __builtin_amdgcn_global_load_lds(
      (const __attribute__((address_space(1))) void*)g,
      (__attribute__((address_space(3))) void*)l, 16, 0, 0);
}

static __device__ __forceinline__ int cvtpk(float lo, float hi) {
  int w;
  asm("v_cvt_pk_bf16_f32 %0, %1, %2" : "=v"(w) : "v"(lo), "v"(hi));
  return w;
}
// v_permlane32_swap_b32: x <- {x_lo, y_lo}, y <- {x_hi, y_hi}
static __device__ __forceinline__ void plswap(int& x, int& y) {
  asm("v_permlane32_swap_b32 %0, %1" : "+v"(x), "+v"(y));
}

#define VMCNT0() asm volatile("s_waitcnt vmcnt(0)" ::: "memory")
#define BARRIER()                                        \
  do {                                                   \
    asm volatile("" ::: "memory");                       \
    __builtin_amdgcn_s_barrier();                        \
    asm volatile("" ::: "memory");                       \
  } while (0)

// ---------------- GN partial stats: 1024 blocks, one 4-channel slice each ----------------
// slot (grp*8 + slice) <- {sum, sumsq} over 4 ch x 1024 t. No atomics, no init.
__global__ __launch_bounds__(256) void gn_stats_kernel(const float* __restrict__ x,
                                                       float* __restrict__ stats) {
  int id = blockIdx.x;                 // (b*32+g)*8 + slice
  int grp = id >> 3, slice = id & 7;
  const float* xb = x + ((size_t)grp * 32 + slice * 4) * 1024;
  int tid = threadIdx.x;
  float s = 0.f, sq = 0.f;
  const float4* x4 = (const float4*)xb;
#pragma unroll
  for (int i = 0; i < 4; ++i) {
    float4 v = x4[i * 256 + tid];
    s  += v.x + v.y + v.z + v.w;
    sq += v.x * v.x + v.y * v.y + v.z * v.z + v.w * v.w;
  }
#pragma unroll
  for (int off = 32; off; off >>= 1) { s += __shfl_down(s, off); sq += __shfl_down(sq, off); }
  __shared__ float red[8];
  int wv = tid >> 6;
  if ((tid & 63) == 0) { red[wv] = s; red[4 + wv] = sq; }
  __syncthreads();
  if (tid == 0) {
    s  = red[0] + red[1] + red[2] + red[3];
    sq = red[4] + red[5] + red[6] + red[7];
    stats[id * 2]     = s;
    stats[id * 2 + 1] = sq;
  }
}

// ---------------- fused: GN apply (blocks 0..511) + weight cast (512..2559) ----------------
__global__ __launch_bounds__(512) void pre_kernel(const float* __restrict__ x,
                                                  const float* __restrict__ gw,
                                                  const float* __restrict__ gb,
                                                  bf16* __restrict__ xnT,
                                                  const float* __restrict__ qkv_w,
                                                  bf16* __restrict__ wq,
                                                  const float* __restrict__ proj_w,
                                                  bf16* __restrict__ wp,
                                                  const float* __restrict__ stats) {
  int blk = blockIdx.x;
  int tid = threadIdx.x;
  if (blk >= 512) {
    int i = (blk - 512) * 512 + tid;
    const int na4 = 3072 * 1024 / 4;
    const float* src; bf16* dst;
    if (i < na4) { src = qkv_w; dst = wq; }
    else         { src = proj_w; dst = wp; i -= na4; }
    float4 v = ((const float4*)src)[i];
    bf16x4 o = { (bf16)v.x, (bf16)v.y, (bf16)v.z, (bf16)v.w };
    *(bf16x4*)(dst + 4ll * i) = o;
    return;
  }
  int id = blk;
  int b = id >> 7, g = (id >> 2) & 31, qtr = id & 3;
  const float* xb = x + ((size_t)b * 1024 + g * 32) * 1024;   // 32 ch x 1024 t

  // stats: sum the group's 8 partial slots (wave-uniform scalar reads)
  const float* st = stats + (size_t)(id >> 2) * 16;
  float s = 0.f, sq = 0.f;
#pragma unroll
  for (int i = 0; i < 8; ++i) { s += st[2 * i]; sq += st[2 * i + 1]; }
  float mean = s * (1.f / 32768.f);
  float var  = sq * (1.f / 32768.f) - mean * mean;
  float rstd = rsqrtf(var + 1e-5f);

  __shared__ bf16 tile[64][36];
  int c = tid >> 4, q = tid & 15;              // load role: ch c, t-quad q
  int r = tid >> 3, q2 = tid & 7;              // store role: row r, ch-quad q2
  float wc = gw[g * 32 + c] * rstd;
  float fb = gb[g * 32 + c] - mean * wc;
  for (int t0 = qtr * 256; t0 < qtr * 256 + 256; t0 += 64) {
    float4 v = *(const float4*)(xb + (size_t)c * 1024 + t0 + q * 4);
    tile[q * 4 + 0][c] = (bf16)(v.x * wc + fb);
    tile[q * 4 + 1][c] = (bf16)(v.y * wc + fb);
    tile[q * 4 + 2][c] = (bf16)(v.z * wc + fb);
    tile[q * 4 + 3][c] = (bf16)(v.w * wc + fb);
    __syncthreads();
    *(bf16x4*)&xnT[((size_t)b * 1024 + t0 + r) * 1024 + g * 32 + q2 * 4] =
        *(bf16x4*)&tile[r][q2 * 4];
    __syncthreads();
  }
}

// ---------------- QKV GEMM v2: 128x192x64, 2 blocks/CU, stage-early dbuf ----------------
__global__ __launch_bounds__(512, 2) void qkv_kernel(
    const bf16* __restrict__ A, const bf16* __restrict__ Bw,
    const float* __restrict__ bias,
    bf16* __restrict__ qkT, bf16* __restrict__ vC) {
  extern __shared__ __align__(16) bf16 smem[];
  // elems: A(d) @ d*8192 (128x64, d=0..1); B(d) @ 16384 + d*12288 (192x64)

  int tid = threadIdx.x, wid = tid >> 6, lane = tid & 63;
  int l15 = lane & 15, l4 = lane >> 4;
  int wr = wid >> 2, wc = wid & 3;            // wave tile: rows wr*64, cols wc*48
  int rsw = (l15 & 7) << 4;

  int sid = (blockIdx.x & 7) * 64 + (blockIdx.x >> 3);   // XCD chunk swizzle (512%8==0)
  int bx = sid & 15, by = (sid >> 4) & 7, z = sid >> 7;
  int m0 = by * 128, n0 = bx * 192;
  const bf16* Ab = A + (size_t)z * 1024 * 1024 + (size_t)m0 * 1024;
  const bf16* Bb = Bw + (size_t)n0 * 1024;

  int srow = tid >> 3;                    // 0..63
  int csw  = (tid & 7) ^ (srow & 7);      // pre-swizzled source chunk
  auto stageA = [&](int d, int kt) {      // 2 gloads/thread (128 rows)
    bf16* dst = smem + d * 8192;
    const bf16* src = Ab + kt * 64 + csw * 8;
#pragma unroll
    for (int L = 0; L < 2; ++L)
      gload_lds16(src + (size_t)(L * 64 + srow) * 1024, dst + (L * 512 + wid * 64) * 8);
  };
  auto stageB = [&](int d, int kt) {      // 3 gloads/thread (192 rows)
    bf16* dst = smem + 16384 + d * 12288;
    const bf16* src = Bb + kt * 64 + csw * 8;
#pragma unroll
    for (int L = 0; L < 3; ++L)
      gload_lds16(src + (size_t)(L * 64 + srow) * 1024, dst + (L * 512 + wid * 64) * 8);
  };

  f32x4 acc[4][3] = {};

  auto compute = [&](int d) {
    const char* Ab8 = (const char*)smem + d * 16384 + wr * 8192;
    const char* Bb8 = (const char*)smem + 32768 + d * 24576;
    bf16x8 bfr[3][2], af[4][2];
#pragma unroll
    for (int ni = 0; ni < 3; ++ni) {
      int rb = (wc * 48 + ni * 16 + l15) * 128;
#pragma unroll
      for (int kk = 0; kk < 2; ++kk)
        bfr[ni][kk] = *(const bf16x8*)(Bb8 + rb + ((kk * 64 + l4 * 16) ^ rsw));
    }
#pragma unroll
    for (int mi = 0; mi < 4; ++mi) {
      int rb = (mi * 16 + l15) * 128;
#pragma unroll
      for (int kk = 0; kk < 2; ++kk)
        af[mi][kk] = *(const bf16x8*)(Ab8 + rb + ((kk * 64 + l4 * 16) ^ rsw));
    }
#pragma unroll
    for (int mi = 0; mi < 4; ++mi)
#pragma unroll
      for (int ni = 0; ni < 3; ++ni)
#pragma unroll
        for (int kk = 0; kk < 2; ++kk)
          acc[mi][ni] = mfma16(af[mi][kk], bfr[ni][kk], acc[mi][ni]);
  };

  stageA(0, 0); stageB(0, 0);
  VMCNT0();
  BARRIER();

  for (int t = 0; t < 16; ++t) {
    int d = t & 1;
    if (t < 15) { stageB(d ^ 1, t + 1); stageA(d ^ 1, t + 1); }  // before compute
    compute(d);
    VMCNT0();
    BARRIER();
  }

  // ---- epilogue: bias, q/k scale, split write (single head h = bx) ----
  const float scale = 0.35355339059327373f;   // 64^-0.25
  int h = bx;
#pragma unroll
  for (int ni = 0; ni < 3; ++ni) {
    int oin = wc * 48 + ni * 16;              // 0..176, wave-uniform
    float bv = bias[n0 + oin + l15];
#pragma unroll
    for (int mi = 0; mi < 4; ++mi) {
      int tb = m0 + wr * 64 + mi * 16 + l4 * 4;
      f32x4 v = acc[mi][ni];
      if (oin < 128) {                        // q|k -> qkT[b][t][h*128 + oin]
#pragma unroll
        for (int i = 0; i < 4; ++i)
          qkT[((size_t)z * 1024 + tb + i) * 2048 + h * 128 + oin + l15] =
              (bf16)((v[i] + bv) * scale);
      } else {                                // v -> vC[(b*16+h)][c][t]
        bf16x4 st = { (bf16)(v[0] + bv), (bf16)(v[1] + bv),
                      (bf16)(v[2] + bv), (bf16)(v[3] + bv) };
        *(bf16x4*)&vC[(((size_t)z * 16 + h) * 64 + (oin - 128 + l15)) * 1024 + tb] = st;
      }
    }
  }
}

// ---------------- proj GEMM v2: 128x64x64, 2 blocks/CU, stage-early dbuf ----------------
__global__ __launch_bounds__(512, 2) void proj_kernel(
    const bf16* __restrict__ A, const bf16* __restrict__ Bw,
    const float* __restrict__ bias,
    const float* __restrict__ xres, float* __restrict__ out) {
  extern __shared__ __align__(16) bf16 smem[];
  // elems: A(d) @ d*8192 (128x64, d=0..1); B(d) @ 16384 + d*4096 (64x64)

  int tid = threadIdx.x, wid = tid >> 6, lane = tid & 63;
  int l15 = lane & 15, l4 = lane >> 4;
  int wr = wid >> 2, wc = wid & 3;             // wave tile: rows wr*64, cols wc*16
  int rsw = (l15 & 7) << 4;

  int sid = (blockIdx.x & 7) * 64 + (blockIdx.x >> 3);   // XCD chunk swizzle (512%8==0)
  int bx = sid & 15, by = (sid >> 4) & 7, z = sid >> 7;
  int m0 = by * 128, n0 = bx * 64;
  const bf16* Ab = A + (size_t)z * 1024 * 1024 + (size_t)m0 * 1024;
  const bf16* Bb = Bw + (size_t)n0 * 1024;

  int srow = tid >> 3;                    // 0..63
  int csw  = (tid & 7) ^ (srow & 7);      // pre-swizzled source chunk
  auto stageA = [&](int d, int kt) {      // 2 gloads/thread (128 rows)
    bf16* dst = smem + d * 8192;
    const bf16* src = Ab + kt * 64 + csw * 8;
#pragma unroll
    for (int L = 0; L < 2; ++L)
      gload_lds16(src + (size_t)(L * 64 + srow) * 1024, dst + (L * 512 + wid * 64) * 8);
  };
  auto stageB = [&](int d, int kt) {      // 1 gload/thread (64 rows)
    bf16* dst = smem + 16384 + d * 4096;
    const bf16* src = Bb + kt * 64 + csw * 8;
    gload_lds16(src + (size_t)srow * 1024, dst + (wid * 64) * 8);
  };

  f32x4 acc[4] = {};

  auto compute = [&](int d) {
    const char* Ab8 = (const char*)smem + d * 16384 + wr * 8192;
    const char* Bb8 = (const char*)smem + 32768 + d * 8192;
    bf16x8 bfr[2], af[4][2];
    int rbB = (wc * 16 + l15) * 128;
#pragma unroll
    for (int kk = 0; kk < 2; ++kk)
      bfr[kk] = *(const bf16x8*)(Bb8 + rbB + ((kk * 64 + l4 * 16) ^ rsw));
#pragma unroll
    for (int mi = 0; mi < 4; ++mi) {
      int rb = (mi * 16 + l15) * 128;
#pragma unroll
      for (int kk = 0; kk < 2; ++kk)
        af[mi][kk] = *(const bf16x8*)(Ab8 + rb + ((kk * 64 + l4 * 16) ^ rsw));
    }
#pragma unroll
    for (int mi = 0; mi < 4; ++mi)
#pragma unroll
      for (int kk = 0; kk < 2; ++kk)
        acc[mi] = mfma16(af[mi][kk], bfr[kk], acc[mi]);
  };

  stageA(0, 0); stageB(0, 0);
  VMCNT0();
  BARRIER();

  for (int t = 0; t < 16; ++t) {
    int d = t & 1;
    if (t < 15) { stageB(d ^ 1, t + 1); stageA(d ^ 1, t + 1); }  // before compute
    compute(d);
    VMCNT0();
    BARRIER();
  }

  // ---- epilogue: bias + residual, transposed fp32 write ----
  int o = n0 + wc * 16 + l15;
  float bv = bias[o];
#pragma unroll
  for (int mi = 0; mi < 4; ++mi) {
    int tb = m0 + wr * 64 + mi * 16 + l4 * 4;
    size_t base = ((size_t)z * 1024 + o) * 1024 + tb;
    float4 xr = *(const float4*)(xres + base);
    f32x4 v = acc[mi];
    float4 ov = { xr.x + v[0] + bv, xr.y + v[1] + bv,
                  xr.z + v[2] + bv, xr.w + v[3] + bv };
    *(float4*)(out + base) = ov;
  }
}

// ---------------- flash attention v8: SBLK=128 (two 64-subtiles per barrier) ----------------
__global__ __launch_bounds__(256, 2) void attn_kernel(const bf16* __restrict__ qkT,
                                                      const bf16* __restrict__ vC,
                                                      bf16* __restrict__ aT) {
  __shared__ __align__(16) bf16 Kt[2][2][64 * 64];   // [buf][h2][s][d] swizzled, 32 KB
  __shared__ __align__(16) bf16 Vt[2][2][64 * 64];   // [buf][h2][c][s] swizzled, 32 KB

  int id = blockIdx.x;
  int sid = (id & 7) * 64 + (id >> 3);            // bijective XCD swizzle (512 % 8 == 0)
  int head = sid >> 3, tblk = sid & 7;
  int b = head >> 4, h = head & 15;
  int t0 = tblk * 128;
  int tid = threadIdx.x, wid = tid >> 6, lane = tid & 63;
  int l31 = lane & 31, hi = lane >> 5;
  int trow = t0 + wid * 32;                       // 32 t-rows per wave

  const bf16* kbase = qkT + (size_t)b * 1024 * 2048 + h * 128 + 64;
  const bf16* vbase = vC + (size_t)(b * 16 + h) * 64 * 1024;
  int rsw = (lane & 7) << 4;                      // row-XOR ((l31)&7 == lane&7)

  // Q frags: B-operand of mfma32 — col t = l31, k(d) = kb*16 + hi*8 + j
  const bf16* qrow = qkT + ((size_t)b * 1024 + trow + l31) * 2048 + h * 128;
  bf16x8 qf[4];
#pragma unroll
  for (int kb = 0; kb < 4; ++kb) qf[kb] = *(const bf16x8*)(qrow + kb * 16 + hi * 8);

  // stage one 64x64 sub-tile: wave wid owns 8-row groups {2wid, 2wid+1}
  int rl = lane >> 3;
  int scol = (((lane & 7) * 16) ^ (rl << 4)) >> 1;
  auto stage64 = [&](int buf, int h2, int st64) {
    int s0 = st64 * 64;
#pragma unroll
    for (int j = 0; j < 2; ++j) {
      int g8 = wid * 2 + j;
      int r = g8 * 8 + rl;
      gload_lds16(kbase + (size_t)(s0 + r) * 2048 + scol, &Kt[buf][h2][g8 * 512]);
      gload_lds16(vbase + (size_t)r * 1024 + s0 + scol, &Vt[buf][h2][g8 * 512]);
    }
  };
  auto stage = [&](int buf, int st) {             // st = outer tile (128 s)
    stage64(buf, 0, st * 2 + 0);
    stage64(buf, 1, st * 2 + 1);
  };

  float m_run = -1e30f, l_run = 0.f;
  f32x16 oacc[2] = {};                            // O^T[c][t]: col t=l31, 2 c-blocks

  stage(0, 0);
  __syncthreads();

  for (int st = 0; st < 8; ++st) {
    int cur = st & 1;
    if (st < 7) stage(cur ^ 1, st + 1);

#pragma unroll
    for (int h2 = 0; h2 < 2; ++h2) {
      // ---- QK^T swapped: S^T[s][t], 8 mfma32 ----
      const char* Kb = (const char*)Kt[cur][h2];
      f32x16 sf[2] = {};
      __builtin_amdgcn_s_setprio(1);
#pragma unroll
      for (int sb = 0; sb < 2; ++sb) {
        int rowb = (sb * 32 + l31) * 128;         // A-frag row = s
#pragma unroll
        for (int kb = 0; kb < 4; ++kb) {
          bf16x8 kf = *(const bf16x8*)(Kb + rowb + ((kb * 32 + hi * 16) ^ rsw));
          sf[sb] = mfma32(kf, qf[kb], sf[sb]);
        }
      }
      __builtin_amdgcn_s_setprio(0);

      // ---- online softmax: lane owns t=l31; s = sb*32 + (r&3)+8*(r>>2)+4*hi ----
      float mb;
      {
        float m0v = fmaxf(sf[0][0], sf[0][1]);
#pragma unroll
        for (int r = 2; r < 16; ++r) m0v = fmaxf(m0v, sf[0][r]);
#pragma unroll
        for (int r = 0; r < 16; ++r) m0v = fmaxf(m0v, sf[1][r]);
        mb = m0v;
      }
      mb = fmaxf(mb, __shfl_xor(mb, 32));         // other s-half, same t
      if (!__all(mb - m_run <= 8.f)) {            // T13 defer-max
        float mn = fmaxf(m_run, mb);
        float corr = __expf(m_run - mn);
        m_run = mn;
        l_run *= corr;
#pragma unroll
        for (int cb = 0; cb < 2; ++cb)
#pragma unroll
          for (int r = 0; r < 16; ++r) oacc[cb][r] *= corr;
      }

      // ---- P = exp(S - m), packed to bf16 + permlane redistribution (T12) ----
      float sbsum = 0.f;
      bf16x8 pf[4];                               // B-frags for 4 k-blocks of 16 s
#pragma unroll
      for (int sb = 0; sb < 2; ++sb) {
        float p[16];
#pragma unroll
        for (int r = 0; r < 16; ++r) {
          p[r] = __expf(sf[sb][r] - m_run);
          sbsum += p[r];
        }
        int w0 = cvtpk(p[0], p[1]),   w1 = cvtpk(p[2], p[3]);
        int w2 = cvtpk(p[4], p[5]),   w3 = cvtpk(p[6], p[7]);
        int w4 = cvtpk(p[8], p[9]),   w5 = cvtpk(p[10], p[11]);
        int w6 = cvtpk(p[12], p[13]), w7 = cvtpk(p[14], p[15]);
        plswap(w0, w2); plswap(w1, w3);           // ks even: s_local 0..15
        plswap(w4, w6); plswap(w5, w7);           // ks odd:  s_local 16..31
        int4 f0 = { w0, w1, w2, w3 };
        int4 f1 = { w4, w5, w6, w7 };
        pf[sb * 2 + 0] = *(bf16x8*)&f0;
        pf[sb * 2 + 1] = *(bf16x8*)&f1;
      }
      sbsum += __shfl_xor(sbsum, 32);
      l_run += sbsum;

      // ---- PV swapped: O^T += V * P, 8 mfma32 ----
      const char* Vb = (const char*)Vt[cur][h2];
      __builtin_amdgcn_s_setprio(1);
#pragma unroll
      for (int ks = 0; ks < 4; ++ks) {
#pragma unroll
        for (int cb = 0; cb < 2; ++cb) {
          bf16x8 vf = *(const bf16x8*)(Vb + (cb * 32 + l31) * 128 + ((ks * 32 + hi * 16) ^ rsw));
          oacc[cb] = mfma32(vf, pf[ks], oacc[cb]);
        }
      }
      __builtin_amdgcn_s_setprio(0);
    }
    VMCNT0();
    BARRIER();   // once per 128 s
  }

  // ---- epilogue: c = cb*32 + 4*hi + 8*q + i (i = reg&3 contiguous) ----
  float rdiv = 1.f / l_run;                       // lane-local (t = l31)
  int t = trow + l31;
#pragma unroll
  for (int cb = 0; cb < 2; ++cb) {
#pragma unroll
    for (int q = 0; q < 4; ++q) {
      bf16x4 ov = { (bf16)(oacc[cb][q * 4 + 0] * rdiv), (bf16)(oacc[cb][q * 4 + 1] * rdiv),
                    (bf16)(oacc[cb][q * 4 + 2] * rdiv), (bf16)(oacc[cb][q * 4 + 3] * rdiv) };
      int c0 = h * 64 + cb * 32 + hi * 4 + q * 8;
      *(bf16x4*)&aT[((size_t)b * 1024 + t) * 1024 + c0] = ov;
    }
  }
}

extern "C" void kernel_launch(void* const* d_in, const int* in_sizes, int n_in,
                              void* d_out, int out_size, void* d_ws, size_t ws_size,
                              hipStream_t stream) {
  const float* x      = (const float*)d_in[0];
  const float* gw     = (const float*)d_in[1];
  const float* gb     = (const float*)d_in[2];
  const float* qkv_w  = (const float*)d_in[3];
  const float* qkv_b  = (const float*)d_in[4];
  const float* proj_w = (const float*)d_in[5];
  const float* proj_b = (const float*)d_in[6];
  float* out = (float*)d_out;

  char* ws = (char*)d_ws;
  bf16*  wq_bf  = (bf16*)(ws);                         //  6 MB: 3072x1024
  bf16*  wp_bf  = (bf16*)(ws + 6ll  * 1024 * 1024);    //  2 MB: 1024x1024
  bf16*  xnT    = (bf16*)(ws + 8ll  * 1024 * 1024);    //  8 MB: [4][1024][1024]
  bf16*  qkT    = (bf16*)(ws + 16ll * 1024 * 1024);    // 16 MB: [4][1024][2048] (q|k per head)
  bf16*  vC     = (bf16*)(ws + 32ll * 1024 * 1024);    //  8 MB: [64][64][1024]
  bf16*  aT     = (bf16*)(ws + 40ll * 1024 * 1024);    //  8 MB: [4][1024][1024]
  float* gstats = (float*)(ws + 48ll * 1024 * 1024);   //  8 KB: [128][8][2]

  hipFuncSetAttribute(reinterpret_cast<const void*>(qkv_kernel),
                      hipFuncAttributeMaxDynamicSharedMemorySize, 81920);
  hipFuncSetAttribute(reinterpret_cast<const void*>(proj_kernel),
                      hipFuncAttributeMaxDynamicSharedMemorySize, 49152);

  gn_stats_kernel<<<dim3(1024), dim3(256), 0, stream>>>(x, gstats);
  pre_kernel<<<dim3(2560), dim3(512), 0, stream>>>(x, gw, gb, xnT, qkv_w, wq_bf, proj_w, wp_bf, gstats);
  qkv_kernel<<<dim3(512), dim3(512), 81920, stream>>>(xnT, wq_bf, qkv_b, qkT, vC);
  attn_kernel<<<dim3(512), dim3(256), 0, stream>>>(qkT, vC, aT);
  proj_kernel<<<dim3(512), dim3(512), 49152, stream>>>(aT, wp_bf, proj_b, x, out);
}

// Round 18
// 87.231 us; speedup vs baseline: 1.0970x; 1.0036x over previous
//
#include <hip/hip_runtime.h>
#include <hip/hip_bf16.h>

typedef __bf16 bf16;
typedef __bf16 bf16x2 __attribute__((ext_vector_type(2)));
typedef __bf16 bf16x4 __attribute__((ext_vector_type(4)));
typedef __bf16 bf16x8 __attribute__((ext_vector_type(8)));
typedef float  f32x4  __attribute__((ext_vector_type(4)));
typedef float  f32x16 __attribute__((ext_vector_type(16)));

static __device__ __forceinline__ f32x4 mfma16(bf16x8 a, bf16x8 b, f32x4 c) {
  return __builtin_amdgcn_mfma_f32_16x16x32_bf16(a, b, c, 0, 0, 0);
}
static __device__ __forceinline__ f32x16 mfma32(bf16x8 a, bf16x8 b, f32x16 c) {
  return __builtin_amdgcn_mfma_f32_32x32x16_bf16(a, b, c, 0, 0, 0);
}

static __device__ __forceinline__ void gload_lds16(const bf16* g, bf16* l) {
  __builtin_amdgcn_global_load_lds(
      (const __attribute__((address_space(1))) void*)g,
      (__attribute__((address_space(3))) void*)l, 16, 0, 0);
}

static __device__ __forceinline__ int cvtpk(float lo, float hi) {
  int w;
  asm("v_cvt_pk_bf16_f32 %0, %1, %2" : "=v"(w) : "v"(lo), "v"(hi));
  return w;
}
// v_permlane32_swap_b32: x <- {x_lo, y_lo}, y <- {x_hi, y_hi}
static __device__ __forceinline__ void plswap(int& x, int& y) {
  asm("v_permlane32_swap_b32 %0, %1" : "+v"(x), "+v"(y));
}

#define VMCNT0() asm volatile("s_waitcnt vmcnt(0)" ::: "memory")
#define BARRIER()                                        \
  do {                                                   \
    asm volatile("" ::: "memory");                       \
    __builtin_amdgcn_s_barrier();                        \
    asm volatile("" ::: "memory");                       \
  } while (0)

// ---------------- GN partial stats: 1024 blocks, one 4-channel slice each ----------------
__global__ __launch_bounds__(256) void gn_stats_kernel(const float* __restrict__ x,
                                                       float* __restrict__ stats) {
  int id = blockIdx.x;                 // (b*32+g)*8 + slice
  int grp = id >> 3, slice = id & 7;
  const float* xb = x + ((size_t)grp * 32 + slice * 4) * 1024;
  int tid = threadIdx.x;
  float s = 0.f, sq = 0.f;
  const float4* x4 = (const float4*)xb;
#pragma unroll
  for (int i = 0; i < 4; ++i) {
    float4 v = x4[i * 256 + tid];
    s  += v.x + v.y + v.z + v.w;
    sq += v.x * v.x + v.y * v.y + v.z * v.z + v.w * v.w;
  }
#pragma unroll
  for (int off = 32; off; off >>= 1) { s += __shfl_down(s, off); sq += __shfl_down(sq, off); }
  __shared__ float red[8];
  int wv = tid >> 6;
  if ((tid & 63) == 0) { red[wv] = s; red[4 + wv] = sq; }
  __syncthreads();
  if (tid == 0) {
    s  = red[0] + red[1] + red[2] + red[3];
    sq = red[4] + red[5] + red[6] + red[7];
    stats[id * 2]     = s;
    stats[id * 2 + 1] = sq;
  }
}

// ---------------- fused: GN apply (blocks 0..511) + weight cast (512..2559) ----------------
__global__ __launch_bounds__(512) void pre_kernel(const float* __restrict__ x,
                                                  const float* __restrict__ gw,
                                                  const float* __restrict__ gb,
                                                  bf16* __restrict__ xnT,
                                                  const float* __restrict__ qkv_w,
                                                  bf16* __restrict__ wq,
                                                  const float* __restrict__ proj_w,
                                                  bf16* __restrict__ wp,
                                                  const float* __restrict__ stats) {
  int blk = blockIdx.x;
  int tid = threadIdx.x;
  if (blk >= 512) {
    int i = (blk - 512) * 512 + tid;
    const int na4 = 3072 * 1024 / 4;
    const float* src; bf16* dst;
    if (i < na4) { src = qkv_w; dst = wq; }
    else         { src = proj_w; dst = wp; i -= na4; }
    float4 v = ((const float4*)src)[i];
    bf16x4 o = { (bf16)v.x, (bf16)v.y, (bf16)v.z, (bf16)v.w };
    *(bf16x4*)(dst + 4ll * i) = o;
    return;
  }
  int id = blk;
  int b = id >> 7, g = (id >> 2) & 31, qtr = id & 3;
  const float* xb = x + ((size_t)b * 1024 + g * 32) * 1024;   // 32 ch x 1024 t

  const float* st = stats + (size_t)(id >> 2) * 16;
  float s = 0.f, sq = 0.f;
#pragma unroll
  for (int i = 0; i < 8; ++i) { s += st[2 * i]; sq += st[2 * i + 1]; }
  float mean = s * (1.f / 32768.f);
  float var  = sq * (1.f / 32768.f) - mean * mean;
  float rstd = rsqrtf(var + 1e-5f);

  __shared__ bf16 tile[64][36];
  int c = tid >> 4, q = tid & 15;              // load role: ch c, t-quad q
  int r = tid >> 3, q2 = tid & 7;              // store role: row r, ch-quad q2
  float wc = gw[g * 32 + c] * rstd;
  float fb = gb[g * 32 + c] - mean * wc;
  for (int t0 = qtr * 256; t0 < qtr * 256 + 256; t0 += 64) {
    float4 v = *(const float4*)(xb + (size_t)c * 1024 + t0 + q * 4);
    tile[q * 4 + 0][c] = (bf16)(v.x * wc + fb);
    tile[q * 4 + 1][c] = (bf16)(v.y * wc + fb);
    tile[q * 4 + 2][c] = (bf16)(v.z * wc + fb);
    tile[q * 4 + 3][c] = (bf16)(v.w * wc + fb);
    __syncthreads();
    *(bf16x4*)&xnT[((size_t)b * 1024 + t0 + r) * 1024 + g * 32 + q2 * 4] =
        *(bf16x4*)&tile[r][q2 * 4];
    __syncthreads();
  }
}

// ---------------- QKV GEMM v2: 128x192x64, 2 blocks/CU, stage-early dbuf ----------------
__global__ __launch_bounds__(512, 2) void qkv_kernel(
    const bf16* __restrict__ A, const bf16* __restrict__ Bw,
    const float* __restrict__ bias,
    bf16* __restrict__ qkT, bf16* __restrict__ vC) {
  extern __shared__ __align__(16) bf16 smem[];
  // elems: A(d) @ d*8192 (128x64, d=0..1); B(d) @ 16384 + d*12288 (192x64)

  int tid = threadIdx.x, wid = tid >> 6, lane = tid & 63;
  int l15 = lane & 15, l4 = lane >> 4;
  int wr = wid >> 2, wc = wid & 3;            // wave tile: rows wr*64, cols wc*48
  int rsw = (l15 & 7) << 4;

  int sid = (blockIdx.x & 7) * 64 + (blockIdx.x >> 3);   // XCD chunk swizzle (512%8==0)
  int bx = sid & 15, by = (sid >> 4) & 7, z = sid >> 7;
  int m0 = by * 128, n0 = bx * 192;
  const bf16* Ab = A + (size_t)z * 1024 * 1024 + (size_t)m0 * 1024;
  const bf16* Bb = Bw + (size_t)n0 * 1024;

  int srow = tid >> 3;                    // 0..63
  int csw  = (tid & 7) ^ (srow & 7);      // pre-swizzled source chunk
  auto stageA = [&](int d, int kt) {      // 2 gloads/thread (128 rows)
    bf16* dst = smem + d * 8192;
    const bf16* src = Ab + kt * 64 + csw * 8;
#pragma unroll
    for (int L = 0; L < 2; ++L)
      gload_lds16(src + (size_t)(L * 64 + srow) * 1024, dst + (L * 512 + wid * 64) * 8);
  };
  auto stageB = [&](int d, int kt) {      // 3 gloads/thread (192 rows)
    bf16* dst = smem + 16384 + d * 12288;
    const bf16* src = Bb + kt * 64 + csw * 8;
#pragma unroll
    for (int L = 0; L < 3; ++L)
      gload_lds16(src + (size_t)(L * 64 + srow) * 1024, dst + (L * 512 + wid * 64) * 8);
  };

  f32x4 acc[4][3] = {};

  auto compute = [&](int d) {
    const char* Ab8 = (const char*)smem + d * 16384 + wr * 8192;
    const char* Bb8 = (const char*)smem + 32768 + d * 24576;
    bf16x8 bfr[3][2], af[4][2];
#pragma unroll
    for (int ni = 0; ni < 3; ++ni) {
      int rb = (wc * 48 + ni * 16 + l15) * 128;
#pragma unroll
      for (int kk = 0; kk < 2; ++kk)
        bfr[ni][kk] = *(const bf16x8*)(Bb8 + rb + ((kk * 64 + l4 * 16) ^ rsw));
    }
#pragma unroll
    for (int mi = 0; mi < 4; ++mi) {
      int rb = (mi * 16 + l15) * 128;
#pragma unroll
      for (int kk = 0; kk < 2; ++kk)
        af[mi][kk] = *(const bf16x8*)(Ab8 + rb + ((kk * 64 + l4 * 16) ^ rsw));
    }
#pragma unroll
    for (int mi = 0; mi < 4; ++mi)
#pragma unroll
      for (int ni = 0; ni < 3; ++ni)
#pragma unroll
        for (int kk = 0; kk < 2; ++kk)
          acc[mi][ni] = mfma16(af[mi][kk], bfr[ni][kk], acc[mi][ni]);
  };

  stageA(0, 0); stageB(0, 0);
  VMCNT0();
  BARRIER();

  for (int t = 0; t < 16; ++t) {
    int d = t & 1;
    if (t < 15) { stageB(d ^ 1, t + 1); stageA(d ^ 1, t + 1); }  // before compute
    compute(d);
    VMCNT0();
    BARRIER();
  }

  // ---- epilogue: bias, q/k scale, split write (single head h = bx) ----
  const float scale = 0.35355339059327373f;   // 64^-0.25
  int h = bx;
#pragma unroll
  for (int ni = 0; ni < 3; ++ni) {
    int oin = wc * 48 + ni * 16;              // 0..176, wave-uniform
    float bv = bias[n0 + oin + l15];
#pragma unroll
    for (int mi = 0; mi < 4; ++mi) {
      int tb = m0 + wr * 64 + mi * 16 + l4 * 4;
      f32x4 v = acc[mi][ni];
      if (oin < 128) {                        // q|k -> qkT[b][t][h*128 + oin]
#pragma unroll
        for (int i = 0; i < 4; ++i)
          qkT[((size_t)z * 1024 + tb + i) * 2048 + h * 128 + oin + l15] =
              (bf16)((v[i] + bv) * scale);
      } else {                                // v -> vC[(b*16+h)][c][t]
        bf16x4 st = { (bf16)(v[0] + bv), (bf16)(v[1] + bv),
                      (bf16)(v[2] + bv), (bf16)(v[3] + bv) };
        *(bf16x4*)&vC[(((size_t)z * 16 + h) * 64 + (oin - 128 + l15)) * 1024 + tb] = st;
      }
    }
  }
}

// ---------------- proj GEMM v2: 128x64x64, 2 blocks/CU, stage-early dbuf ----------------
__global__ __launch_bounds__(512, 2) void proj_kernel(
    const bf16* __restrict__ A, const bf16* __restrict__ Bw,
    const float* __restrict__ bias,
    const float* __restrict__ xres, float* __restrict__ out) {
  extern __shared__ __align__(16) bf16 smem[];
  // elems: A(d) @ d*8192 (128x64, d=0..1); B(d) @ 16384 + d*4096 (64x64)

  int tid = threadIdx.x, wid = tid >> 6, lane = tid & 63;
  int l15 = lane & 15, l4 = lane >> 4;
  int wr = wid >> 2, wc = wid & 3;             // wave tile: rows wr*64, cols wc*16
  int rsw = (l15 & 7) << 4;

  int sid = (blockIdx.x & 7) * 64 + (blockIdx.x >> 3);   // XCD chunk swizzle (512%8==0)
  int bx = sid & 15, by = (sid >> 4) & 7, z = sid >> 7;
  int m0 = by * 128, n0 = bx * 64;
  const bf16* Ab = A + (size_t)z * 1024 * 1024 + (size_t)m0 * 1024;
  const bf16* Bb = Bw + (size_t)n0 * 1024;

  int srow = tid >> 3;                    // 0..63
  int csw  = (tid & 7) ^ (srow & 7);      // pre-swizzled source chunk
  auto stageA = [&](int d, int kt) {      // 2 gloads/thread (128 rows)
    bf16* dst = smem + d * 8192;
    const bf16* src = Ab + kt * 64 + csw * 8;
#pragma unroll
    for (int L = 0; L < 2; ++L)
      gload_lds16(src + (size_t)(L * 64 + srow) * 1024, dst + (L * 512 + wid * 64) * 8);
  };
  auto stageB = [&](int d, int kt) {      // 1 gload/thread (64 rows)
    bf16* dst = smem + 16384 + d * 4096;
    const bf16* src = Bb + kt * 64 + csw * 8;
    gload_lds16(src + (size_t)srow * 1024, dst + (wid * 64) * 8);
  };

  f32x4 acc[4] = {};

  auto compute = [&](int d) {
    const char* Ab8 = (const char*)smem + d * 16384 + wr * 8192;
    const char* Bb8 = (const char*)smem + 32768 + d * 8192;
    bf16x8 bfr[2], af[4][2];
    int rbB = (wc * 16 + l15) * 128;
#pragma unroll
    for (int kk = 0; kk < 2; ++kk)
      bfr[kk] = *(const bf16x8*)(Bb8 + rbB + ((kk * 64 + l4 * 16) ^ rsw));
#pragma unroll
    for (int mi = 0; mi < 4; ++mi) {
      int rb = (mi * 16 + l15) * 128;
#pragma unroll
      for (int kk = 0; kk < 2; ++kk)
        af[mi][kk] = *(const bf16x8*)(Ab8 + rb + ((kk * 64 + l4 * 16) ^ rsw));
    }
#pragma unroll
    for (int mi = 0; mi < 4; ++mi)
#pragma unroll
      for (int kk = 0; kk < 2; ++kk)
        acc[mi] = mfma16(af[mi][kk], bfr[kk], acc[mi]);
  };

  stageA(0, 0); stageB(0, 0);
  VMCNT0();
  BARRIER();

  for (int t = 0; t < 16; ++t) {
    int d = t & 1;
    if (t < 15) { stageB(d ^ 1, t + 1); stageA(d ^ 1, t + 1); }  // before compute
    compute(d);
    VMCNT0();
    BARRIER();
  }

  // ---- epilogue: bias + residual, transposed fp32 write ----
  int o = n0 + wc * 16 + l15;
  float bv = bias[o];
#pragma unroll
  for (int mi = 0; mi < 4; ++mi) {
    int tb = m0 + wr * 64 + mi * 16 + l4 * 4;
    size_t base = ((size_t)z * 1024 + o) * 1024 + tb;
    float4 xr = *(const float4*)(xres + base);
    f32x4 v = acc[mi];
    float4 ov = { xr.x + v[0] + bv, xr.y + v[1] + bv,
                  xr.z + v[2] + bv, xr.w + v[3] + bv };
    *(float4*)(out + base) = ov;
  }
}

// ---------------- flash attention v9: joint 128-s softmax (T15-lite) ----------------
// v8 staging/layout unchanged. Both 64-s halves processed jointly per outer
// tile: 16-deep QK mfma cluster -> ONE max/defer/rescale per 128 s (math
// identical: exp against joint m_run, single oacc rescale) -> batched
// exp/pack -> 16-deep PV cluster.
__global__ __launch_bounds__(256, 2) void attn_kernel(const bf16* __restrict__ qkT,
                                                      const bf16* __restrict__ vC,
                                                      bf16* __restrict__ aT) {
  __shared__ __align__(16) bf16 Kt[2][2][64 * 64];   // [buf][h2][s][d] swizzled, 32 KB
  __shared__ __align__(16) bf16 Vt[2][2][64 * 64];   // [buf][h2][c][s] swizzled, 32 KB

  int id = blockIdx.x;
  int sid = (id & 7) * 64 + (id >> 3);            // bijective XCD swizzle (512 % 8 == 0)
  int head = sid >> 3, tblk = sid & 7;
  int b = head >> 4, h = head & 15;
  int t0 = tblk * 128;
  int tid = threadIdx.x, wid = tid >> 6, lane = tid & 63;
  int l31 = lane & 31, hi = lane >> 5;
  int trow = t0 + wid * 32;                       // 32 t-rows per wave

  const bf16* kbase = qkT + (size_t)b * 1024 * 2048 + h * 128 + 64;
  const bf16* vbase = vC + (size_t)(b * 16 + h) * 64 * 1024;
  int rsw = (lane & 7) << 4;                      // row-XOR ((l31)&7 == lane&7)

  // Q frags: B-operand of mfma32 — col t = l31, k(d) = kb*16 + hi*8 + j
  const bf16* qrow = qkT + ((size_t)b * 1024 + trow + l31) * 2048 + h * 128;
  bf16x8 qf[4];
#pragma unroll
  for (int kb = 0; kb < 4; ++kb) qf[kb] = *(const bf16x8*)(qrow + kb * 16 + hi * 8);

  // stage one 64x64 sub-tile: wave wid owns 8-row groups {2wid, 2wid+1}
  int rl = lane >> 3;
  int scol = (((lane & 7) * 16) ^ (rl << 4)) >> 1;
  auto stage64 = [&](int buf, int h2, int st64) {
    int s0 = st64 * 64;
#pragma unroll
    for (int j = 0; j < 2; ++j) {
      int g8 = wid * 2 + j;
      int r = g8 * 8 + rl;
      gload_lds16(kbase + (size_t)(s0 + r) * 2048 + scol, &Kt[buf][h2][g8 * 512]);
      gload_lds16(vbase + (size_t)r * 1024 + s0 + scol, &Vt[buf][h2][g8 * 512]);
    }
  };
  auto stage = [&](int buf, int st) {             // st = outer tile (128 s)
    stage64(buf, 0, st * 2 + 0);
    stage64(buf, 1, st * 2 + 1);
  };

  float m_run = -1e30f, l_run = 0.f;
  f32x16 oacc[2] = {};                            // O^T[c][t]: col t=l31, 2 c-blocks

  stage(0, 0);
  __syncthreads();

  for (int st = 0; st < 8; ++st) {
    int cur = st & 1;
    if (st < 7) stage(cur ^ 1, st + 1);

    // ---- QK^T swapped, BOTH halves: 16 mfma32 in one cluster ----
    f32x16 sf[2][2] = {};                         // [h2][sb]
    __builtin_amdgcn_s_setprio(1);
#pragma unroll
    for (int h2 = 0; h2 < 2; ++h2) {
      const char* Kb = (const char*)Kt[cur][h2];
#pragma unroll
      for (int sb = 0; sb < 2; ++sb) {
        int rowb = (sb * 32 + l31) * 128;         // A-frag row = s
#pragma unroll
        for (int kb = 0; kb < 4; ++kb) {
          bf16x8 kf = *(const bf16x8*)(Kb + rowb + ((kb * 32 + hi * 16) ^ rsw));
          sf[h2][sb] = mfma32(kf, qf[kb], sf[h2][sb]);
        }
      }
    }
    __builtin_amdgcn_s_setprio(0);

    // ---- joint softmax over all 128 s: one max, one defer-check, one rescale ----
    float mb;
    {
      float m0v = fmaxf(sf[0][0][0], sf[0][0][1]);
#pragma unroll
      for (int h2 = 0; h2 < 2; ++h2)
#pragma unroll
        for (int sb = 0; sb < 2; ++sb)
#pragma unroll
          for (int r = 0; r < 16; ++r) m0v = fmaxf(m0v, sf[h2][sb][r]);
      mb = m0v;
    }
    mb = fmaxf(mb, __shfl_xor(mb, 32));           // other s-half, same t
    if (!__all(mb - m_run <= 8.f)) {              // T13 defer-max
      float mn = fmaxf(m_run, mb);
      float corr = __expf(m_run - mn);
      m_run = mn;
      l_run *= corr;
#pragma unroll
      for (int cb = 0; cb < 2; ++cb)
#pragma unroll
        for (int r = 0; r < 16; ++r) oacc[cb][r] *= corr;
    }

    // ---- P = exp(S - m) both halves, packed + permlane (T12) ----
    float sbsum = 0.f;
    bf16x8 pf[2][4];                              // [h2][ks]
#pragma unroll
    for (int h2 = 0; h2 < 2; ++h2) {
#pragma unroll
      for (int sb = 0; sb < 2; ++sb) {
        float p[16];
#pragma unroll
        for (int r = 0; r < 16; ++r) {
          p[r] = __expf(sf[h2][sb][r] - m_run);
          sbsum += p[r];
        }
        int w0 = cvtpk(p[0], p[1]),   w1 = cvtpk(p[2], p[3]);
        int w2 = cvtpk(p[4], p[5]),   w3 = cvtpk(p[6], p[7]);
        int w4 = cvtpk(p[8], p[9]),   w5 = cvtpk(p[10], p[11]);
        int w6 = cvtpk(p[12], p[13]), w7 = cvtpk(p[14], p[15]);
        plswap(w0, w2); plswap(w1, w3);           // ks even: s_local 0..15
        plswap(w4, w6); plswap(w5, w7);           // ks odd:  s_local 16..31
        int4 f0 = { w0, w1, w2, w3 };
        int4 f1 = { w4, w5, w6, w7 };
        pf[h2][sb * 2 + 0] = *(bf16x8*)&f0;
        pf[h2][sb * 2 + 1] = *(bf16x8*)&f1;
      }
    }
    sbsum += __shfl_xor(sbsum, 32);
    l_run += sbsum;

    // ---- PV swapped, BOTH halves: 16 mfma32 in one cluster ----
    __builtin_amdgcn_s_setprio(1);
#pragma unroll
    for (int h2 = 0; h2 < 2; ++h2) {
      const char* Vb = (const char*)Vt[cur][h2];
#pragma unroll
      for (int ks = 0; ks < 4; ++ks) {
#pragma unroll
        for (int cb = 0; cb < 2; ++cb) {
          bf16x8 vf = *(const bf16x8*)(Vb + (cb * 32 + l31) * 128 + ((ks * 32 + hi * 16) ^ rsw));
          oacc[cb] = mfma32(vf, pf[h2][ks], oacc[cb]);
        }
      }
    }
    __builtin_amdgcn_s_setprio(0);
    VMCNT0();
    BARRIER();   // once per 128 s
  }

  // ---- epilogue: c = cb*32 + 4*hi + 8*q + i (i = reg&3 contiguous) ----
  float rdiv = 1.f / l_run;                       // lane-local (t = l31)
  int t = trow + l31;
#pragma unroll
  for (int cb = 0; cb < 2; ++cb) {
#pragma unroll
    for (int q = 0; q < 4; ++q) {
      bf16x4 ov = { (bf16)(oacc[cb][q * 4 + 0] * rdiv), (bf16)(oacc[cb][q * 4 + 1] * rdiv),
                    (bf16)(oacc[cb][q * 4 + 2] * rdiv), (bf16)(oacc[cb][q * 4 + 3] * rdiv) };
      int c0 = h * 64 + cb * 32 + hi * 4 + q * 8;
      *(bf16x4*)&aT[((size_t)b * 1024 + t) * 1024 + c0] = ov;
    }
  }
}

extern "C" void kernel_launch(void* const* d_in, const int* in_sizes, int n_in,
                              void* d_out, int out_size, void* d_ws, size_t ws_size,
                              hipStream_t stream) {
  const float* x      = (const float*)d_in[0];
  const float* gw     = (const float*)d_in[1];
  const float* gb     = (const float*)d_in[2];
  const float* qkv_w  = (const float*)d_in[3];
  const float* qkv_b  = (const float*)d_in[4];
  const float* proj_w = (const float*)d_in[5];
  const float* proj_b = (const float*)d_in[6];
  float* out = (float*)d_out;

  char* ws = (char*)d_ws;
  bf16*  wq_bf  = (bf16*)(ws);                         //  6 MB: 3072x1024
  bf16*  wp_bf  = (bf16*)(ws + 6ll  * 1024 * 1024);    //  2 MB: 1024x1024
  bf16*  xnT    = (bf16*)(ws + 8ll  * 1024 * 1024);    //  8 MB: [4][1024][1024]
  bf16*  qkT    = (bf16*)(ws + 16ll * 1024 * 1024);    // 16 MB: [4][1024][2048] (q|k per head)
  bf16*  vC     = (bf16*)(ws + 32ll * 1024 * 1024);    //  8 MB: [64][64][1024]
  bf16*  aT     = (bf16*)(ws + 40ll * 1024 * 1024);    //  8 MB: [4][1024][1024]
  float* gstats = (float*)(ws + 48ll * 1024 * 1024);   //  8 KB: [128][8][2]

  hipFuncSetAttribute(reinterpret_cast<const void*>(qkv_kernel),
                      hipFuncAttributeMaxDynamicSharedMemorySize, 81920);
  hipFuncSetAttribute(reinterpret_cast<const void*>(proj_kernel),
                      hipFuncAttributeMaxDynamicSharedMemorySize, 49152);

  gn_stats_kernel<<<dim3(1024), dim3(256), 0, stream>>>(x, gstats);
  pre_kernel<<<dim3(2560), dim3(512), 0, stream>>>(x, gw, gb, xnT, qkv_w, wq_bf, proj_w, wp_bf, gstats);
  qkv_kernel<<<dim3(512), dim3(512), 81920, stream>>>(xnT, wq_bf, qkv_b, qkT, vC);
  attn_kernel<<<dim3(512), dim3(256), 0, stream>>>(qkT, vC, aT);
  proj_kernel<<<dim3(512), dim3(512), 49152, stream>>>(aT, wp_bf, proj_b, x, out);
}